// Round 5
// baseline (291.871 us; speedup 1.0000x reference)
//
#include <hip/hip_runtime.h>
#include <hip/hip_fp16.h>

// GCN, N=50000 nodes, E=800000 edges, 128->128(relu)->64, fp32 compute.
// CSR entries packed to 4B: (norm fp16 << 16) | src (src < 65536).
// Aggregation kernels split the feature dim across XCDs (blockIdx%8 ==
// XCD round-robin) so each XCD's gather footprint (3.2 MB) fits its 4 MB L2.

#define Nn 50000
#define Ne 800000
#define SCAN_B ((Nn + 1023) / 1024)   // 49 blocks

// ---------------- degree count ----------------
__global__ __launch_bounds__(256) void k_count(const int* __restrict__ col,
                                               int* __restrict__ degi) {
  int e = blockIdx.x * 256 + threadIdx.x;
  if (e < Ne) atomicAdd(&degi[col[e]], 1);
}

// ---------------- scan phase 1: block-local exclusive scan + dis ----------------
__global__ __launch_bounds__(1024) void k_scan1(const int* __restrict__ degi,
                                                int* __restrict__ rowptr,
                                                float* __restrict__ dis,
                                                int* __restrict__ bsum) {
  __shared__ int wsum[16];
  int tid = threadIdx.x;
  int lane = tid & 63, wid = tid >> 6;
  int i = blockIdx.x * 1024 + tid;
  int v = (i < Nn) ? degi[i] : 0;
  if (i < Nn) dis[i] = rsqrtf((float)(v + 1));   // self-loop adds 1
  int incl = v;
  #pragma unroll
  for (int off = 1; off < 64; off <<= 1) {
    int t = __shfl_up(incl, off);
    if (lane >= off) incl += t;
  }
  if (lane == 63) wsum[wid] = incl;
  __syncthreads();
  if (wid == 0) {
    int wv = (lane < 16) ? wsum[lane] : 0;
    #pragma unroll
    for (int off = 1; off < 16; off <<= 1) {
      int t = __shfl_up(wv, off);
      if (lane >= off) wv += t;
    }
    if (lane < 16) wsum[lane] = wv;  // inclusive over wave totals
  }
  __syncthreads();
  int woff = (wid > 0) ? wsum[wid - 1] : 0;
  if (i < Nn) rowptr[i] = woff + incl - v;       // block-local exclusive
  if (tid == 0) bsum[blockIdx.x] = wsum[15];     // block total
}

// ---------------- scan phase 2: exclusive scan of 49 block sums ----------------
__global__ __launch_bounds__(64) void k_scan2(int* __restrict__ bsum,
                                              int* __restrict__ rowptr) {
  int lane = threadIdx.x;
  int v = (lane < SCAN_B) ? bsum[lane] : 0;
  int incl = v;
  #pragma unroll
  for (int off = 1; off < 64; off <<= 1) {
    int t = __shfl_up(incl, off);
    if (lane >= off) incl += t;
  }
  if (lane < SCAN_B) bsum[lane] = incl - v;      // exclusive block offsets
  if (lane == 63) rowptr[Nn] = incl;             // == Ne
}

// ---------------- scan phase 3: add block offsets ----------------
__global__ __launch_bounds__(1024) void k_scan3(int* __restrict__ rowptr,
                                                const int* __restrict__ bsum) {
  int i = blockIdx.x * 1024 + threadIdx.x;
  if (i < Nn) rowptr[i] += bsum[blockIdx.x];
}

// ---------------- CSR fill: packed (norm_fp16 << 16) | src ----------------
__global__ __launch_bounds__(256) void k_fill(const int* __restrict__ row,
                                              const int* __restrict__ col,
                                              const float* __restrict__ dis,
                                              const int* __restrict__ rowptr,
                                              int* __restrict__ cursor,
                                              unsigned int* __restrict__ csr) {
  int e = blockIdx.x * 256 + threadIdx.x;
  if (e >= Ne) return;
  int r = row[e], c = col[e];
  int pos = rowptr[c] + atomicAdd(&cursor[c], 1);
  __half hn = __float2half(dis[r] * dis[c]);
  csr[pos] = ((unsigned int)__half_as_ushort(hn) << 16) | (unsigned int)r;
}

// ---------------- tiled GEMM: H[n, ldo](fp16) = X[n,128] @ W[128, ldo] ----------------
__global__ __launch_bounds__(256) void k_gemm(const float* __restrict__ X,
                                              const float* __restrict__ W,
                                              __half* __restrict__ H,
                                              int n, int ldo) {
  __shared__ float Wl[128 * 64];   // [k][c] c within slice
  __shared__ float Xl[64 * 128];   // [node][k]
  const int tid = threadIdx.x;
  const int tx = tid & 15, ty = tid >> 4;
  const int base = blockIdx.x * 64;
  const int colbase = blockIdx.y * 64;

  {
    const float4* Wg = (const float4*)W;
    float4* Ws = (float4*)Wl;
    const int ldw4 = ldo >> 2, cb4 = colbase >> 2;
    #pragma unroll
    for (int i = 0; i < 8; ++i) {
      int idx = tid + i * 256;          // 0..2047
      int r = idx >> 4, c4 = idx & 15;
      Ws[idx] = Wg[r * ldw4 + cb4 + c4];
    }
  }
  {
    const float4* Xg = (const float4*)X;
    float4* Xs = (float4*)Xl;
    #pragma unroll
    for (int i = 0; i < 8; ++i) {
      int idx = tid + i * 256;          // 0..2047
      int node = base + (idx >> 5);
      int nc = node < n ? node : n - 1;
      Xs[idx] = Xg[(size_t)nc * 32 + (idx & 31)];
    }
  }
  __syncthreads();

  float a[4][4];
  #pragma unroll
  for (int m = 0; m < 4; ++m)
    #pragma unroll
    for (int c = 0; c < 4; ++c) a[m][c] = 0.f;

  #pragma unroll 4
  for (int k = 0; k < 128; k += 4) {
    float4 w0 = *(const float4*)&Wl[(k + 0) * 64 + (tx << 2)];
    float4 w1 = *(const float4*)&Wl[(k + 1) * 64 + (tx << 2)];
    float4 w2 = *(const float4*)&Wl[(k + 2) * 64 + (tx << 2)];
    float4 w3 = *(const float4*)&Wl[(k + 3) * 64 + (tx << 2)];
    #pragma unroll
    for (int m = 0; m < 4; ++m) {
      float4 xv = *(const float4*)&Xl[(ty * 4 + m) * 128 + k];
      a[m][0] = fmaf(xv.x, w0.x, a[m][0]);
      a[m][0] = fmaf(xv.y, w1.x, a[m][0]);
      a[m][0] = fmaf(xv.z, w2.x, a[m][0]);
      a[m][0] = fmaf(xv.w, w3.x, a[m][0]);
      a[m][1] = fmaf(xv.x, w0.y, a[m][1]);
      a[m][1] = fmaf(xv.y, w1.y, a[m][1]);
      a[m][1] = fmaf(xv.z, w2.y, a[m][1]);
      a[m][1] = fmaf(xv.w, w3.y, a[m][1]);
      a[m][2] = fmaf(xv.x, w0.z, a[m][2]);
      a[m][2] = fmaf(xv.y, w1.z, a[m][2]);
      a[m][2] = fmaf(xv.z, w2.z, a[m][2]);
      a[m][2] = fmaf(xv.w, w3.z, a[m][2]);
      a[m][3] = fmaf(xv.x, w0.w, a[m][3]);
      a[m][3] = fmaf(xv.y, w1.w, a[m][3]);
      a[m][3] = fmaf(xv.z, w2.w, a[m][3]);
      a[m][3] = fmaf(xv.w, w3.w, a[m][3]);
    }
  }

  #pragma unroll
  for (int m = 0; m < 4; ++m) {
    int node = base + ty * 4 + m;
    if (node < n) {
      __half2 p0 = __float22half2_rn(make_float2(a[m][0], a[m][1]));
      __half2 p1 = __float22half2_rn(make_float2(a[m][2], a[m][3]));
      uint2 st;
      st.x = *(const unsigned int*)&p0;
      st.y = *(const unsigned int*)&p1;
      *(uint2*)(H + (size_t)node * ldo + colbase + (tx << 2)) = st;
    }
  }
}

// ---------------- aggregate 128 feats (+bias, relu), column-quarter split ----------------
// blockIdx&3 = feature quarter (32 feats); XCD=blockIdx%8 => each XCD only
// touches a 3.2 MB column slice of H (fits 4 MB L2). 4 nodes/wave, 16 lanes
// each, half2 per lane => one fully-used 64B line per node per gather.
__global__ __launch_bounds__(256) void k_agg128(const __half* __restrict__ H,
                                                const unsigned int* __restrict__ csr,
                                                const int* __restrict__ rowptr,
                                                const float* __restrict__ dis,
                                                const float* __restrict__ bias,
                                                float* __restrict__ Out, int n) {
  const int qb = blockIdx.x & 3;                 // feature quarter
  const int ng = blockIdx.x >> 2;                // node group (16 nodes)
  const int wid = threadIdx.x >> 6, lane = threadIdx.x & 63;
  const int sub = lane >> 4, fl = lane & 15;     // node-in-wave, half2 idx
  const int qoff = qb * 16;                      // half2 offset within row
  int v = ng * 16 + wid * 4 + sub;
  if (v >= n) return;
  int s = rowptr[v], e = rowptr[v + 1];
  float d = dis[v];
  float sw = d * d;                              // self-loop norm = 1/deg
  const __half2* Hp = (const __half2*)H;         // 64 half2 per row
  float2 h = __half22float2(Hp[(size_t)v * 64 + qoff + fl]);
  float a0 = h.x * sw, a1 = h.y * sw;
  int i = s;
  for (; i + 8 <= e; i += 8) {
    unsigned int e0 = csr[i + 0], e1 = csr[i + 1], e2 = csr[i + 2], e3 = csr[i + 3];
    unsigned int e4 = csr[i + 4], e5 = csr[i + 5], e6 = csr[i + 6], e7 = csr[i + 7];
    float2 h0 = __half22float2(Hp[(size_t)(e0 & 0xFFFFu) * 64 + qoff + fl]);
    float2 h1 = __half22float2(Hp[(size_t)(e1 & 0xFFFFu) * 64 + qoff + fl]);
    float2 h2 = __half22float2(Hp[(size_t)(e2 & 0xFFFFu) * 64 + qoff + fl]);
    float2 h3 = __half22float2(Hp[(size_t)(e3 & 0xFFFFu) * 64 + qoff + fl]);
    float2 h4 = __half22float2(Hp[(size_t)(e4 & 0xFFFFu) * 64 + qoff + fl]);
    float2 h5 = __half22float2(Hp[(size_t)(e5 & 0xFFFFu) * 64 + qoff + fl]);
    float2 h6 = __half22float2(Hp[(size_t)(e6 & 0xFFFFu) * 64 + qoff + fl]);
    float2 h7 = __half22float2(Hp[(size_t)(e7 & 0xFFFFu) * 64 + qoff + fl]);
    float w0 = __half2float(__ushort_as_half((unsigned short)(e0 >> 16)));
    float w1 = __half2float(__ushort_as_half((unsigned short)(e1 >> 16)));
    float w2 = __half2float(__ushort_as_half((unsigned short)(e2 >> 16)));
    float w3 = __half2float(__ushort_as_half((unsigned short)(e3 >> 16)));
    float w4 = __half2float(__ushort_as_half((unsigned short)(e4 >> 16)));
    float w5 = __half2float(__ushort_as_half((unsigned short)(e5 >> 16)));
    float w6 = __half2float(__ushort_as_half((unsigned short)(e6 >> 16)));
    float w7 = __half2float(__ushort_as_half((unsigned short)(e7 >> 16)));
    a0 = fmaf(w0, h0.x, a0); a1 = fmaf(w0, h0.y, a1);
    a0 = fmaf(w1, h1.x, a0); a1 = fmaf(w1, h1.y, a1);
    a0 = fmaf(w2, h2.x, a0); a1 = fmaf(w2, h2.y, a1);
    a0 = fmaf(w3, h3.x, a0); a1 = fmaf(w3, h3.y, a1);
    a0 = fmaf(w4, h4.x, a0); a1 = fmaf(w4, h4.y, a1);
    a0 = fmaf(w5, h5.x, a0); a1 = fmaf(w5, h5.y, a1);
    a0 = fmaf(w6, h6.x, a0); a1 = fmaf(w6, h6.y, a1);
    a0 = fmaf(w7, h7.x, a0); a1 = fmaf(w7, h7.y, a1);
  }
  for (; i < e; ++i) {
    unsigned int ee = csr[i];
    float2 hs = __half22float2(Hp[(size_t)(ee & 0xFFFFu) * 64 + qoff + fl]);
    float w = __half2float(__ushort_as_half((unsigned short)(ee >> 16)));
    a0 = fmaf(w, hs.x, a0);
    a1 = fmaf(w, hs.y, a1);
  }
  float2 b = *(const float2*)(bias + qb * 32 + 2 * fl);
  a0 = fmaxf(a0 + b.x, 0.f);
  a1 = fmaxf(a1 + b.y, 0.f);
  *(float2*)(Out + (size_t)v * 128 + qb * 32 + 2 * fl) = make_float2(a0, a1);
}

// ---------------- aggregate 64 feats (+bias), column-half split ----------------
// blockIdx&1 = feature half (32 feats); per-XCD footprint 3.2 MB (fits L2).
__global__ __launch_bounds__(256) void k_agg64(const __half* __restrict__ H,
                                               const unsigned int* __restrict__ csr,
                                               const int* __restrict__ rowptr,
                                               const float* __restrict__ dis,
                                               const float* __restrict__ bias,
                                               float* __restrict__ Out, int n) {
  const int hb = blockIdx.x & 1;                 // feature half
  const int ng = blockIdx.x >> 1;                // node group (16 nodes)
  const int wid = threadIdx.x >> 6, lane = threadIdx.x & 63;
  const int sub = lane >> 4, fl = lane & 15;
  const int hoff = hb * 16;                      // half2 offset within row
  int v = ng * 16 + wid * 4 + sub;
  if (v >= n) return;
  int s = rowptr[v], e = rowptr[v + 1];
  float d = dis[v];
  float sw = d * d;
  const __half2* Hp = (const __half2*)H;         // 32 half2 per row
  float2 h = __half22float2(Hp[(size_t)v * 32 + hoff + fl]);
  float a0 = h.x * sw, a1 = h.y * sw;
  int i = s;
  for (; i + 8 <= e; i += 8) {
    unsigned int e0 = csr[i + 0], e1 = csr[i + 1], e2 = csr[i + 2], e3 = csr[i + 3];
    unsigned int e4 = csr[i + 4], e5 = csr[i + 5], e6 = csr[i + 6], e7 = csr[i + 7];
    float2 h0 = __half22float2(Hp[(size_t)(e0 & 0xFFFFu) * 32 + hoff + fl]);
    float2 h1 = __half22float2(Hp[(size_t)(e1 & 0xFFFFu) * 32 + hoff + fl]);
    float2 h2 = __half22float2(Hp[(size_t)(e2 & 0xFFFFu) * 32 + hoff + fl]);
    float2 h3 = __half22float2(Hp[(size_t)(e3 & 0xFFFFu) * 32 + hoff + fl]);
    float2 h4 = __half22float2(Hp[(size_t)(e4 & 0xFFFFu) * 32 + hoff + fl]);
    float2 h5 = __half22float2(Hp[(size_t)(e5 & 0xFFFFu) * 32 + hoff + fl]);
    float2 h6 = __half22float2(Hp[(size_t)(e6 & 0xFFFFu) * 32 + hoff + fl]);
    float2 h7 = __half22float2(Hp[(size_t)(e7 & 0xFFFFu) * 32 + hoff + fl]);
    float w0 = __half2float(__ushort_as_half((unsigned short)(e0 >> 16)));
    float w1 = __half2float(__ushort_as_half((unsigned short)(e1 >> 16)));
    float w2 = __half2float(__ushort_as_half((unsigned short)(e2 >> 16)));
    float w3 = __half2float(__ushort_as_half((unsigned short)(e3 >> 16)));
    float w4 = __half2float(__ushort_as_half((unsigned short)(e4 >> 16)));
    float w5 = __half2float(__ushort_as_half((unsigned short)(e5 >> 16)));
    float w6 = __half2float(__ushort_as_half((unsigned short)(e6 >> 16)));
    float w7 = __half2float(__ushort_as_half((unsigned short)(e7 >> 16)));
    a0 = fmaf(w0, h0.x, a0); a1 = fmaf(w0, h0.y, a1);
    a0 = fmaf(w1, h1.x, a0); a1 = fmaf(w1, h1.y, a1);
    a0 = fmaf(w2, h2.x, a0); a1 = fmaf(w2, h2.y, a1);
    a0 = fmaf(w3, h3.x, a0); a1 = fmaf(w3, h3.y, a1);
    a0 = fmaf(w4, h4.x, a0); a1 = fmaf(w4, h4.y, a1);
    a0 = fmaf(w5, h5.x, a0); a1 = fmaf(w5, h5.y, a1);
    a0 = fmaf(w6, h6.x, a0); a1 = fmaf(w6, h6.y, a1);
    a0 = fmaf(w7, h7.x, a0); a1 = fmaf(w7, h7.y, a1);
  }
  for (; i < e; ++i) {
    unsigned int ee = csr[i];
    float2 hs = __half22float2(Hp[(size_t)(ee & 0xFFFFu) * 32 + hoff + fl]);
    float w = __half2float(__ushort_as_half((unsigned short)(ee >> 16)));
    a0 = fmaf(w, hs.x, a0);
    a1 = fmaf(w, hs.y, a1);
  }
  float2 b = *(const float2*)(bias + hb * 32 + 2 * fl);
  *(float2*)(Out + (size_t)v * 64 + hb * 32 + 2 * fl) =
      make_float2(a0 + b.x, a1 + b.y);
}

extern "C" void kernel_launch(void* const* d_in, const int* in_sizes, int n_in,
                              void* d_out, int out_size, void* d_ws, size_t ws_size,
                              hipStream_t stream) {
  const float* x  = (const float*)d_in[0];
  const int*   ei = (const int*)d_in[1];    // [2, E] row-major
  const int*   row = ei;                    // edge_index[0] (source)
  const int*   col = ei + Ne;               // edge_index[1] (dest / segment)
  const float* W1 = (const float*)d_in[2];
  const float* b1 = (const float*)d_in[3];
  const float* W2 = (const float*)d_in[4];
  const float* b2 = (const float*)d_in[5];
  float* out = (float*)d_out;

  char* ws = (char*)d_ws;
  size_t off = 0;
  auto alloc = [&](size_t bytes) -> void* {
    void* p = ws + off;
    off += (bytes + 255) & ~(size_t)255;
    return p;
  };
  int*    degi   = (int*)   alloc(Nn * sizeof(int));
  int*    cursor = (int*)   alloc(Nn * sizeof(int));
  int*    rowptr = (int*)   alloc((Nn + 1) * sizeof(int));
  float*  dis    = (float*) alloc(Nn * sizeof(float));
  int*    bsum   = (int*)   alloc(64 * sizeof(int));
  unsigned int* csr = (unsigned int*)alloc((size_t)Ne * sizeof(unsigned int)); // 3.2 MB
  __half* H1     = (__half*)alloc((size_t)Nn * 128 * sizeof(__half));  // 12.8 MB
  float*  H1b    = (float*) alloc((size_t)Nn * 128 * sizeof(float));   // 25.6 MB
  __half* H2     = (__half*)alloc((size_t)Nn * 64 * sizeof(__half));   // 6.4 MB

  hipMemsetAsync(degi, 0, Nn * sizeof(int), stream);
  hipMemsetAsync(cursor, 0, Nn * sizeof(int), stream);

  const int EB  = (Ne + 255) / 256;         // 3125
  const int NGB = (Nn + 15) / 16;           // 3125 node groups (16 nodes each)
  const int GT  = (Nn + 63) / 64;           // 782 node tiles (gemm)

  k_count<<<EB, 256, 0, stream>>>(col, degi);
  k_scan1<<<SCAN_B, 1024, 0, stream>>>(degi, rowptr, dis, bsum);
  k_scan2<<<1, 64, 0, stream>>>(bsum, rowptr);
  k_scan3<<<SCAN_B, 1024, 0, stream>>>(rowptr, bsum);
  k_fill<<<EB, 256, 0, stream>>>(row, col, dis, rowptr, cursor, csr);

  // layer 1: H1 = fp16(x @ W1) ; H1b = relu(agg(H1) + b1)
  k_gemm<<<dim3(GT, 2), 256, 0, stream>>>(x, W1, H1, Nn, 128);
  k_agg128<<<NGB * 4, 256, 0, stream>>>(H1, csr, rowptr, dis, b1, H1b, Nn);

  // layer 2: H2 = fp16(H1b @ W2) ; out = agg(H2) + b2
  k_gemm<<<dim3(GT, 1), 256, 0, stream>>>(H1b, W2, H2, Nn, 64);
  k_agg64<<<NGB * 2, 256, 0, stream>>>(H2, csr, rowptr, dis, b2, out, Nn);
}

// Round 6
// 261.006 us; speedup vs baseline: 1.1183x; 1.1183x over previous
//
#include <hip/hip_runtime.h>
#include <hip/hip_fp16.h>

// GCN, N=50000 nodes, E=800000 edges, 128->128(relu)->64, fp32 compute.
// CSR entries packed to 4B: (norm fp16 << 16) | src (src < 65536).
// Aggregation: full-row fp16 gathers, 16B/lane (uint4), 4 nodes per wave,
// 4-deep unroll => 16 edge-rows in flight per wave, 4x fewer gather instrs.

#define Nn 50000
#define Ne 800000
#define SCAN_B ((Nn + 1023) / 1024)   // 49 blocks

// ---------------- degree count ----------------
__global__ __launch_bounds__(256) void k_count(const int* __restrict__ col,
                                               int* __restrict__ degi) {
  int e = blockIdx.x * 256 + threadIdx.x;
  if (e < Ne) atomicAdd(&degi[col[e]], 1);
}

// ---------------- scan phase 1: block-local exclusive scan + dis ----------------
__global__ __launch_bounds__(1024) void k_scan1(const int* __restrict__ degi,
                                                int* __restrict__ rowptr,
                                                float* __restrict__ dis,
                                                int* __restrict__ bsum) {
  __shared__ int wsum[16];
  int tid = threadIdx.x;
  int lane = tid & 63, wid = tid >> 6;
  int i = blockIdx.x * 1024 + tid;
  int v = (i < Nn) ? degi[i] : 0;
  if (i < Nn) dis[i] = rsqrtf((float)(v + 1));   // self-loop adds 1
  int incl = v;
  #pragma unroll
  for (int off = 1; off < 64; off <<= 1) {
    int t = __shfl_up(incl, off);
    if (lane >= off) incl += t;
  }
  if (lane == 63) wsum[wid] = incl;
  __syncthreads();
  if (wid == 0) {
    int wv = (lane < 16) ? wsum[lane] : 0;
    #pragma unroll
    for (int off = 1; off < 16; off <<= 1) {
      int t = __shfl_up(wv, off);
      if (lane >= off) wv += t;
    }
    if (lane < 16) wsum[lane] = wv;  // inclusive over wave totals
  }
  __syncthreads();
  int woff = (wid > 0) ? wsum[wid - 1] : 0;
  if (i < Nn) rowptr[i] = woff + incl - v;       // block-local exclusive
  if (tid == 0) bsum[blockIdx.x] = wsum[15];     // block total
}

// ---------------- scan phase 2: exclusive scan of 49 block sums ----------------
__global__ __launch_bounds__(64) void k_scan2(int* __restrict__ bsum,
                                              int* __restrict__ rowptr) {
  int lane = threadIdx.x;
  int v = (lane < SCAN_B) ? bsum[lane] : 0;
  int incl = v;
  #pragma unroll
  for (int off = 1; off < 64; off <<= 1) {
    int t = __shfl_up(incl, off);
    if (lane >= off) incl += t;
  }
  if (lane < SCAN_B) bsum[lane] = incl - v;      // exclusive block offsets
  if (lane == 63) rowptr[Nn] = incl;             // == Ne
}

// ---------------- scan phase 3: add block offsets ----------------
__global__ __launch_bounds__(1024) void k_scan3(int* __restrict__ rowptr,
                                                const int* __restrict__ bsum) {
  int i = blockIdx.x * 1024 + threadIdx.x;
  if (i < Nn) rowptr[i] += bsum[blockIdx.x];
}

// ---------------- CSR fill: packed (norm_fp16 << 16) | src ----------------
__global__ __launch_bounds__(256) void k_fill(const int* __restrict__ row,
                                              const int* __restrict__ col,
                                              const float* __restrict__ dis,
                                              const int* __restrict__ rowptr,
                                              int* __restrict__ cursor,
                                              unsigned int* __restrict__ csr) {
  int e = blockIdx.x * 256 + threadIdx.x;
  if (e >= Ne) return;
  int r = row[e], c = col[e];
  int pos = rowptr[c] + atomicAdd(&cursor[c], 1);
  __half hn = __float2half(dis[r] * dis[c]);
  csr[pos] = ((unsigned int)__half_as_ushort(hn) << 16) | (unsigned int)r;
}

// ---------------- tiled GEMM: H[n, ldo](fp16) = X[n,128] @ W[128, ldo] ----------------
__global__ __launch_bounds__(256) void k_gemm(const float* __restrict__ X,
                                              const float* __restrict__ W,
                                              __half* __restrict__ H,
                                              int n, int ldo) {
  __shared__ float Wl[128 * 64];   // [k][c] c within slice
  __shared__ float Xl[64 * 128];   // [node][k]
  const int tid = threadIdx.x;
  const int tx = tid & 15, ty = tid >> 4;
  const int base = blockIdx.x * 64;
  const int colbase = blockIdx.y * 64;

  {
    const float4* Wg = (const float4*)W;
    float4* Ws = (float4*)Wl;
    const int ldw4 = ldo >> 2, cb4 = colbase >> 2;
    #pragma unroll
    for (int i = 0; i < 8; ++i) {
      int idx = tid + i * 256;          // 0..2047
      int r = idx >> 4, c4 = idx & 15;
      Ws[idx] = Wg[r * ldw4 + cb4 + c4];
    }
  }
  {
    const float4* Xg = (const float4*)X;
    float4* Xs = (float4*)Xl;
    #pragma unroll
    for (int i = 0; i < 8; ++i) {
      int idx = tid + i * 256;          // 0..2047
      int node = base + (idx >> 5);
      int nc = node < n ? node : n - 1;
      Xs[idx] = Xg[(size_t)nc * 32 + (idx & 31)];
    }
  }
  __syncthreads();

  float a[4][4];
  #pragma unroll
  for (int m = 0; m < 4; ++m)
    #pragma unroll
    for (int c = 0; c < 4; ++c) a[m][c] = 0.f;

  #pragma unroll 4
  for (int k = 0; k < 128; k += 4) {
    float4 w0 = *(const float4*)&Wl[(k + 0) * 64 + (tx << 2)];
    float4 w1 = *(const float4*)&Wl[(k + 1) * 64 + (tx << 2)];
    float4 w2 = *(const float4*)&Wl[(k + 2) * 64 + (tx << 2)];
    float4 w3 = *(const float4*)&Wl[(k + 3) * 64 + (tx << 2)];
    #pragma unroll
    for (int m = 0; m < 4; ++m) {
      float4 xv = *(const float4*)&Xl[(ty * 4 + m) * 128 + k];
      a[m][0] = fmaf(xv.x, w0.x, a[m][0]);
      a[m][0] = fmaf(xv.y, w1.x, a[m][0]);
      a[m][0] = fmaf(xv.z, w2.x, a[m][0]);
      a[m][0] = fmaf(xv.w, w3.x, a[m][0]);
      a[m][1] = fmaf(xv.x, w0.y, a[m][1]);
      a[m][1] = fmaf(xv.y, w1.y, a[m][1]);
      a[m][1] = fmaf(xv.z, w2.y, a[m][1]);
      a[m][1] = fmaf(xv.w, w3.y, a[m][1]);
      a[m][2] = fmaf(xv.x, w0.z, a[m][2]);
      a[m][2] = fmaf(xv.y, w1.z, a[m][2]);
      a[m][2] = fmaf(xv.z, w2.z, a[m][2]);
      a[m][2] = fmaf(xv.w, w3.z, a[m][2]);
      a[m][3] = fmaf(xv.x, w0.w, a[m][3]);
      a[m][3] = fmaf(xv.y, w1.w, a[m][3]);
      a[m][3] = fmaf(xv.z, w2.w, a[m][3]);
      a[m][3] = fmaf(xv.w, w3.w, a[m][3]);
    }
  }

  #pragma unroll
  for (int m = 0; m < 4; ++m) {
    int node = base + ty * 4 + m;
    if (node < n) {
      __half2 p0 = __float22half2_rn(make_float2(a[m][0], a[m][1]));
      __half2 p1 = __float22half2_rn(make_float2(a[m][2], a[m][3]));
      uint2 st;
      st.x = *(const unsigned int*)&p0;
      st.y = *(const unsigned int*)&p1;
      *(uint2*)(H + (size_t)node * ldo + colbase + (tx << 2)) = st;
    }
  }
}

__device__ __forceinline__ float2 h2f(unsigned int u) {
  return __half22float2(*(const __half2*)&u);
}
__device__ __forceinline__ float wdec(unsigned int u) {
  return __half2float(__ushort_as_half((unsigned short)(u >> 16)));
}

// ---------------- aggregate 128 feats (+bias, relu) ----------------
// 4 nodes/wave, 16 lanes/node, uint4 (8 feats) per lane => one gather instr
// covers 4 edge-rows; 4-deep unroll => 16 rows in flight per wave.
__global__ __launch_bounds__(256) void k_agg128(const __half* __restrict__ H,
                                                const unsigned int* __restrict__ csr,
                                                const int* __restrict__ rowptr,
                                                const float* __restrict__ dis,
                                                const float* __restrict__ bias,
                                                float* __restrict__ Out, int n) {
  const int wid = threadIdx.x >> 6, lane = threadIdx.x & 63;
  const int sub = lane >> 4, fl = lane & 15;     // node-in-wave, uint4 idx
  int v = blockIdx.x * 16 + wid * 4 + sub;
  if (v >= n) return;
  int s = rowptr[v], e = rowptr[v + 1];
  float d = dis[v];
  float sw = d * d;                              // self-loop norm = 1/deg
  const uint4* Hq = (const uint4*)H;             // 16 uint4 per 256B row
  uint4 hv = Hq[(size_t)v * 16 + fl];
  float2 p0 = h2f(hv.x), p1 = h2f(hv.y), p2 = h2f(hv.z), p3 = h2f(hv.w);
  float a0 = p0.x * sw, a1 = p0.y * sw, a2 = p1.x * sw, a3 = p1.y * sw;
  float a4 = p2.x * sw, a5 = p2.y * sw, a6 = p3.x * sw, a7 = p3.y * sw;
  int i = s;
  for (; i + 4 <= e; i += 4) {
    unsigned int u0 = csr[i + 0], u1 = csr[i + 1];
    unsigned int u2 = csr[i + 2], u3 = csr[i + 3];
    uint4 q0 = Hq[(size_t)(u0 & 0xFFFFu) * 16 + fl];
    uint4 q1 = Hq[(size_t)(u1 & 0xFFFFu) * 16 + fl];
    uint4 q2 = Hq[(size_t)(u2 & 0xFFFFu) * 16 + fl];
    uint4 q3 = Hq[(size_t)(u3 & 0xFFFFu) * 16 + fl];
    float w0 = wdec(u0), w1 = wdec(u1), w2 = wdec(u2), w3 = wdec(u3);
    float2 t;
    t = h2f(q0.x); a0 = fmaf(w0, t.x, a0); a1 = fmaf(w0, t.y, a1);
    t = h2f(q0.y); a2 = fmaf(w0, t.x, a2); a3 = fmaf(w0, t.y, a3);
    t = h2f(q0.z); a4 = fmaf(w0, t.x, a4); a5 = fmaf(w0, t.y, a5);
    t = h2f(q0.w); a6 = fmaf(w0, t.x, a6); a7 = fmaf(w0, t.y, a7);
    t = h2f(q1.x); a0 = fmaf(w1, t.x, a0); a1 = fmaf(w1, t.y, a1);
    t = h2f(q1.y); a2 = fmaf(w1, t.x, a2); a3 = fmaf(w1, t.y, a3);
    t = h2f(q1.z); a4 = fmaf(w1, t.x, a4); a5 = fmaf(w1, t.y, a5);
    t = h2f(q1.w); a6 = fmaf(w1, t.x, a6); a7 = fmaf(w1, t.y, a7);
    t = h2f(q2.x); a0 = fmaf(w2, t.x, a0); a1 = fmaf(w2, t.y, a1);
    t = h2f(q2.y); a2 = fmaf(w2, t.x, a2); a3 = fmaf(w2, t.y, a3);
    t = h2f(q2.z); a4 = fmaf(w2, t.x, a4); a5 = fmaf(w2, t.y, a5);
    t = h2f(q2.w); a6 = fmaf(w2, t.x, a6); a7 = fmaf(w2, t.y, a7);
    t = h2f(q3.x); a0 = fmaf(w3, t.x, a0); a1 = fmaf(w3, t.y, a1);
    t = h2f(q3.y); a2 = fmaf(w3, t.x, a2); a3 = fmaf(w3, t.y, a3);
    t = h2f(q3.z); a4 = fmaf(w3, t.x, a4); a5 = fmaf(w3, t.y, a5);
    t = h2f(q3.w); a6 = fmaf(w3, t.x, a6); a7 = fmaf(w3, t.y, a7);
  }
  for (; i < e; ++i) {
    unsigned int u = csr[i];
    uint4 q = Hq[(size_t)(u & 0xFFFFu) * 16 + fl];
    float w = wdec(u);
    float2 t;
    t = h2f(q.x); a0 = fmaf(w, t.x, a0); a1 = fmaf(w, t.y, a1);
    t = h2f(q.y); a2 = fmaf(w, t.x, a2); a3 = fmaf(w, t.y, a3);
    t = h2f(q.z); a4 = fmaf(w, t.x, a4); a5 = fmaf(w, t.y, a5);
    t = h2f(q.w); a6 = fmaf(w, t.x, a6); a7 = fmaf(w, t.y, a7);
  }
  const float4* Bq = (const float4*)bias;        // 32 float4 per 128 floats
  float4 b0 = Bq[fl * 2], b1 = Bq[fl * 2 + 1];
  float4 o0 = make_float4(fmaxf(a0 + b0.x, 0.f), fmaxf(a1 + b0.y, 0.f),
                          fmaxf(a2 + b0.z, 0.f), fmaxf(a3 + b0.w, 0.f));
  float4 o1 = make_float4(fmaxf(a4 + b1.x, 0.f), fmaxf(a5 + b1.y, 0.f),
                          fmaxf(a6 + b1.z, 0.f), fmaxf(a7 + b1.w, 0.f));
  float4* Oq = (float4*)(Out + (size_t)v * 128);
  Oq[fl * 2] = o0;
  Oq[fl * 2 + 1] = o1;
}

// ---------------- aggregate 64 feats (+bias, no relu) ----------------
// 4 nodes/wave, 16 lanes/node, uint2 (4 feats) per lane.
__global__ __launch_bounds__(256) void k_agg64(const __half* __restrict__ H,
                                               const unsigned int* __restrict__ csr,
                                               const int* __restrict__ rowptr,
                                               const float* __restrict__ dis,
                                               const float* __restrict__ bias,
                                               float* __restrict__ Out, int n) {
  const int wid = threadIdx.x >> 6, lane = threadIdx.x & 63;
  const int sub = lane >> 4, fl = lane & 15;     // node-in-wave, uint2 idx
  int v = blockIdx.x * 16 + wid * 4 + sub;
  if (v >= n) return;
  int s = rowptr[v], e = rowptr[v + 1];
  float d = dis[v];
  float sw = d * d;
  const uint2* Hq = (const uint2*)H;             // 16 uint2 per 128B row
  uint2 hv = Hq[(size_t)v * 16 + fl];
  float2 p0 = h2f(hv.x), p1 = h2f(hv.y);
  float a0 = p0.x * sw, a1 = p0.y * sw, a2 = p1.x * sw, a3 = p1.y * sw;
  int i = s;
  for (; i + 4 <= e; i += 4) {
    unsigned int u0 = csr[i + 0], u1 = csr[i + 1];
    unsigned int u2 = csr[i + 2], u3 = csr[i + 3];
    uint2 q0 = Hq[(size_t)(u0 & 0xFFFFu) * 16 + fl];
    uint2 q1 = Hq[(size_t)(u1 & 0xFFFFu) * 16 + fl];
    uint2 q2 = Hq[(size_t)(u2 & 0xFFFFu) * 16 + fl];
    uint2 q3 = Hq[(size_t)(u3 & 0xFFFFu) * 16 + fl];
    float w0 = wdec(u0), w1 = wdec(u1), w2 = wdec(u2), w3 = wdec(u3);
    float2 t;
    t = h2f(q0.x); a0 = fmaf(w0, t.x, a0); a1 = fmaf(w0, t.y, a1);
    t = h2f(q0.y); a2 = fmaf(w0, t.x, a2); a3 = fmaf(w0, t.y, a3);
    t = h2f(q1.x); a0 = fmaf(w1, t.x, a0); a1 = fmaf(w1, t.y, a1);
    t = h2f(q1.y); a2 = fmaf(w1, t.x, a2); a3 = fmaf(w1, t.y, a3);
    t = h2f(q2.x); a0 = fmaf(w2, t.x, a0); a1 = fmaf(w2, t.y, a1);
    t = h2f(q2.y); a2 = fmaf(w2, t.x, a2); a3 = fmaf(w2, t.y, a3);
    t = h2f(q3.x); a0 = fmaf(w3, t.x, a0); a1 = fmaf(w3, t.y, a1);
    t = h2f(q3.y); a2 = fmaf(w3, t.x, a2); a3 = fmaf(w3, t.y, a3);
  }
  for (; i < e; ++i) {
    unsigned int u = csr[i];
    uint2 q = Hq[(size_t)(u & 0xFFFFu) * 16 + fl];
    float w = wdec(u);
    float2 t;
    t = h2f(q.x); a0 = fmaf(w, t.x, a0); a1 = fmaf(w, t.y, a1);
    t = h2f(q.y); a2 = fmaf(w, t.x, a2); a3 = fmaf(w, t.y, a3);
  }
  const float4* Bq = (const float4*)bias;        // 16 float4 per 64 floats
  float4 b = Bq[fl];
  float4 o = make_float4(a0 + b.x, a1 + b.y, a2 + b.z, a3 + b.w);
  ((float4*)(Out + (size_t)v * 64))[fl] = o;
}

extern "C" void kernel_launch(void* const* d_in, const int* in_sizes, int n_in,
                              void* d_out, int out_size, void* d_ws, size_t ws_size,
                              hipStream_t stream) {
  const float* x  = (const float*)d_in[0];
  const int*   ei = (const int*)d_in[1];    // [2, E] row-major
  const int*   row = ei;                    // edge_index[0] (source)
  const int*   col = ei + Ne;               // edge_index[1] (dest / segment)
  const float* W1 = (const float*)d_in[2];
  const float* b1 = (const float*)d_in[3];
  const float* W2 = (const float*)d_in[4];
  const float* b2 = (const float*)d_in[5];
  float* out = (float*)d_out;

  char* ws = (char*)d_ws;
  size_t off = 0;
  auto alloc = [&](size_t bytes) -> void* {
    void* p = ws + off;
    off += (bytes + 255) & ~(size_t)255;
    return p;
  };
  int*    degi   = (int*)   alloc(Nn * sizeof(int));
  int*    cursor = (int*)   alloc(Nn * sizeof(int));
  int*    rowptr = (int*)   alloc((Nn + 1) * sizeof(int));
  float*  dis    = (float*) alloc(Nn * sizeof(float));
  int*    bsum   = (int*)   alloc(64 * sizeof(int));
  unsigned int* csr = (unsigned int*)alloc((size_t)Ne * sizeof(unsigned int)); // 3.2 MB
  __half* H1     = (__half*)alloc((size_t)Nn * 128 * sizeof(__half));  // 12.8 MB
  float*  H1b    = (float*) alloc((size_t)Nn * 128 * sizeof(float));   // 25.6 MB
  __half* H2     = (__half*)alloc((size_t)Nn * 64 * sizeof(__half));   // 6.4 MB

  hipMemsetAsync(degi, 0, Nn * sizeof(int), stream);
  hipMemsetAsync(cursor, 0, Nn * sizeof(int), stream);

  const int EB  = (Ne + 255) / 256;         // 3125
  const int NGB = (Nn + 15) / 16;           // 3125 node groups (16 nodes each)
  const int GT  = (Nn + 63) / 64;           // 782 node tiles (gemm)

  k_count<<<EB, 256, 0, stream>>>(col, degi);
  k_scan1<<<SCAN_B, 1024, 0, stream>>>(degi, rowptr, dis, bsum);
  k_scan2<<<1, 64, 0, stream>>>(bsum, rowptr);
  k_scan3<<<SCAN_B, 1024, 0, stream>>>(rowptr, bsum);
  k_fill<<<EB, 256, 0, stream>>>(row, col, dis, rowptr, cursor, csr);

  // layer 1: H1 = fp16(x @ W1) ; H1b = relu(agg(H1) + b1)
  k_gemm<<<dim3(GT, 2), 256, 0, stream>>>(x, W1, H1, Nn, 128);
  k_agg128<<<NGB, 256, 0, stream>>>(H1, csr, rowptr, dis, b1, H1b, Nn);

  // layer 2: H2 = fp16(H1b @ W2) ; out = agg(H2) + b2
  k_gemm<<<dim3(GT, 1), 256, 0, stream>>>(H1b, W2, H2, Nn, 64);
  k_agg64<<<NGB, 256, 0, stream>>>(H2, csr, rowptr, dis, b2, out, Nn);
}

// Round 7
// 221.445 us; speedup vs baseline: 1.3180x; 1.1786x over previous
//
#include <hip/hip_runtime.h>
#include <hip/hip_fp16.h>

// GCN, N=50000 nodes, E=800000 edges, 128->128(relu)->64, fp32 accum.
// CSR entries packed to 4B: (norm fp16 << 16) | src (src < 65536).
// k_count emits per-edge bucket rank (no atomic in k_fill).
// GEMMs: fp16 MFMA (v_mfma_f32_16x16x32_f16), W transposed into LDS so the
// B-fragment reads are contiguous ds_read_b128. Aggregation: full-row fp16
// gathers, 16B/lane (uint4), 4 nodes/wave, 4-deep edge unroll.

#define Nn 50000
#define Ne 800000
#define SCAN_B ((Nn + 1023) / 1024)   // 49 blocks

using f16x8 = _Float16 __attribute__((ext_vector_type(8)));
using f32x4 = float __attribute__((ext_vector_type(4)));

// ---------------- degree count + within-bucket rank ----------------
__global__ __launch_bounds__(256) void k_count(const int* __restrict__ col,
                                               int* __restrict__ degi,
                                               unsigned short* __restrict__ rank) {
  int e = blockIdx.x * 256 + threadIdx.x;
  if (e < Ne) rank[e] = (unsigned short)atomicAdd(&degi[col[e]], 1);
}

// ---------------- scan phase 1: block-local exclusive scan + dis ----------------
__global__ __launch_bounds__(1024) void k_scan1(const int* __restrict__ degi,
                                                int* __restrict__ rowptr,
                                                float* __restrict__ dis,
                                                int* __restrict__ bsum) {
  __shared__ int wsum[16];
  int tid = threadIdx.x;
  int lane = tid & 63, wid = tid >> 6;
  int i = blockIdx.x * 1024 + tid;
  int v = (i < Nn) ? degi[i] : 0;
  if (i < Nn) dis[i] = rsqrtf((float)(v + 1));   // self-loop adds 1
  int incl = v;
  #pragma unroll
  for (int off = 1; off < 64; off <<= 1) {
    int t = __shfl_up(incl, off);
    if (lane >= off) incl += t;
  }
  if (lane == 63) wsum[wid] = incl;
  __syncthreads();
  if (wid == 0) {
    int wv = (lane < 16) ? wsum[lane] : 0;
    #pragma unroll
    for (int off = 1; off < 16; off <<= 1) {
      int t = __shfl_up(wv, off);
      if (lane >= off) wv += t;
    }
    if (lane < 16) wsum[lane] = wv;  // inclusive over wave totals
  }
  __syncthreads();
  int woff = (wid > 0) ? wsum[wid - 1] : 0;
  if (i < Nn) rowptr[i] = woff + incl - v;       // block-local exclusive
  if (tid == 0) bsum[blockIdx.x] = wsum[15];     // block total
}

// ---------------- scan phase 2: exclusive scan of 49 block sums ----------------
__global__ __launch_bounds__(64) void k_scan2(int* __restrict__ bsum,
                                              int* __restrict__ rowptr) {
  int lane = threadIdx.x;
  int v = (lane < SCAN_B) ? bsum[lane] : 0;
  int incl = v;
  #pragma unroll
  for (int off = 1; off < 64; off <<= 1) {
    int t = __shfl_up(incl, off);
    if (lane >= off) incl += t;
  }
  if (lane < SCAN_B) bsum[lane] = incl - v;      // exclusive block offsets
  if (lane == 63) rowptr[Nn] = incl;             // == Ne
}

// ---------------- scan phase 3: add block offsets ----------------
__global__ __launch_bounds__(1024) void k_scan3(int* __restrict__ rowptr,
                                                const int* __restrict__ bsum) {
  int i = blockIdx.x * 1024 + threadIdx.x;
  if (i < Nn) rowptr[i] += bsum[blockIdx.x];
}

// ---------------- CSR fill: packed (norm_fp16 << 16) | src, no atomic ----------------
__global__ __launch_bounds__(256) void k_fill(const int* __restrict__ row,
                                              const int* __restrict__ col,
                                              const float* __restrict__ dis,
                                              const int* __restrict__ rowptr,
                                              const unsigned short* __restrict__ rank,
                                              unsigned int* __restrict__ csr) {
  int e = blockIdx.x * 256 + threadIdx.x;
  if (e >= Ne) return;
  int r = row[e], c = col[e];
  int pos = rowptr[c] + (int)rank[e];
  __half hn = __float2half(dis[r] * dis[c]);
  csr[pos] = ((unsigned int)__half_as_ushort(hn) << 16) | (unsigned int)r;
}

// ---------------- MFMA GEMM: H[n, LDO](fp16) = X[n,128] @ W[128, LDO] ----------------
// Block 256 = 4 waves; tile = 64 nodes x LDO cols, K=128 in 4 MFMA steps.
// A-frag: A[m=lane&15][k=quad*8+j]  (X row-major in LDS, contiguous 16B)
// B-frag: B[k=quad*8+j][n=lane&15]  (W TRANSPOSED in LDS -> contiguous 16B)
// C/D:    col=lane&15, row=quad*4+reg   (m89-verified layout)
template <int LDO>
__global__ __launch_bounds__(256) void k_gemm_mfma(const float* __restrict__ X,
                                                   const float* __restrict__ W,
                                                   __half* __restrict__ H, int n) {
  __shared__ _Float16 Xs[64 * 136];        // 64 rows x (128+8 pad)
  __shared__ _Float16 Wts[LDO * 136];      // transposed W, LDO rows x 128 (+pad)
  const int tid = threadIdx.x;
  const int base = blockIdx.x * 64;

  // stage Wt: read W[k][c] as float4 (coalesced), scatter fp16 to Wts[c][k]
  {
    constexpr int C4 = LDO / 4;            // float4s per W row
    for (int idx4 = tid; idx4 < 32 * LDO; idx4 += 256) {
      int k = idx4 / C4;
      int c = (idx4 % C4) * 4;
      float4 wv = ((const float4*)W)[idx4];
      Wts[(c + 0) * 136 + k] = (_Float16)wv.x;
      Wts[(c + 1) * 136 + k] = (_Float16)wv.y;
      Wts[(c + 2) * 136 + k] = (_Float16)wv.z;
      Wts[(c + 3) * 136 + k] = (_Float16)wv.w;
    }
  }
  // stage X tile: fp32 -> fp16, row-major, 8 feats per unit
  {
    for (int u = tid; u < 64 * 16; u += 256) {
      int r = u >> 4, seg = u & 15;
      int node = base + r;
      if (node >= n) node = n - 1;
      const float4* xg = (const float4*)(X + (size_t)node * 128 + seg * 8);
      float4 x0 = xg[0], x1 = xg[1];
      f16x8 hv;
      hv[0] = (_Float16)x0.x; hv[1] = (_Float16)x0.y;
      hv[2] = (_Float16)x0.z; hv[3] = (_Float16)x0.w;
      hv[4] = (_Float16)x1.x; hv[5] = (_Float16)x1.y;
      hv[6] = (_Float16)x1.z; hv[7] = (_Float16)x1.w;
      *(f16x8*)&Xs[r * 136 + seg * 8] = hv;
    }
  }
  __syncthreads();

  const int w = tid >> 6, lane = tid & 63;
  const int quad = lane >> 4, mrow = lane & 15;
  constexpr int NCT = LDO / 16;

  f32x4 acc[NCT];
  #pragma unroll
  for (int ct = 0; ct < NCT; ++ct) acc[ct] = (f32x4){0.f, 0.f, 0.f, 0.f};

  #pragma unroll
  for (int ko = 0; ko < 4; ++ko) {
    f16x8 av = *(const f16x8*)&Xs[(w * 16 + mrow) * 136 + ko * 32 + quad * 8];
    #pragma unroll
    for (int ct = 0; ct < NCT; ++ct) {
      f16x8 bv = *(const f16x8*)&Wts[(ct * 16 + mrow) * 136 + ko * 32 + quad * 8];
      acc[ct] = __builtin_amdgcn_mfma_f32_16x16x32_f16(av, bv, acc[ct], 0, 0, 0);
    }
  }

  #pragma unroll
  for (int ct = 0; ct < NCT; ++ct) {
    #pragma unroll
    for (int r = 0; r < 4; ++r) {
      int node = base + w * 16 + quad * 4 + r;
      if (node < n)
        H[(size_t)node * LDO + ct * 16 + mrow] = __float2half(acc[ct][r]);
    }
  }
}

__device__ __forceinline__ float2 h2f(unsigned int u) {
  return __half22float2(*(const __half2*)&u);
}
__device__ __forceinline__ float wdec(unsigned int u) {
  return __half2float(__ushort_as_half((unsigned short)(u >> 16)));
}

// ---------------- aggregate 128 feats (+bias, relu) ----------------
// 4 nodes/wave, 16 lanes/node, uint4 (8 feats) per lane => one gather instr
// covers 4 edge-rows; 4-deep unroll => 16 rows in flight per wave.
__global__ __launch_bounds__(256) void k_agg128(const __half* __restrict__ H,
                                                const unsigned int* __restrict__ csr,
                                                const int* __restrict__ rowptr,
                                                const float* __restrict__ dis,
                                                const float* __restrict__ bias,
                                                float* __restrict__ Out, int n) {
  const int wid = threadIdx.x >> 6, lane = threadIdx.x & 63;
  const int sub = lane >> 4, fl = lane & 15;     // node-in-wave, uint4 idx
  int v = blockIdx.x * 16 + wid * 4 + sub;
  if (v >= n) return;
  int s = rowptr[v], e = rowptr[v + 1];
  float d = dis[v];
  float sw = d * d;                              // self-loop norm = 1/deg
  const uint4* Hq = (const uint4*)H;             // 16 uint4 per 256B row
  uint4 hv = Hq[(size_t)v * 16 + fl];
  float2 p0 = h2f(hv.x), p1 = h2f(hv.y), p2 = h2f(hv.z), p3 = h2f(hv.w);
  float a0 = p0.x * sw, a1 = p0.y * sw, a2 = p1.x * sw, a3 = p1.y * sw;
  float a4 = p2.x * sw, a5 = p2.y * sw, a6 = p3.x * sw, a7 = p3.y * sw;
  int i = s;
  for (; i + 4 <= e; i += 4) {
    unsigned int u0 = csr[i + 0], u1 = csr[i + 1];
    unsigned int u2 = csr[i + 2], u3 = csr[i + 3];
    uint4 q0 = Hq[(size_t)(u0 & 0xFFFFu) * 16 + fl];
    uint4 q1 = Hq[(size_t)(u1 & 0xFFFFu) * 16 + fl];
    uint4 q2 = Hq[(size_t)(u2 & 0xFFFFu) * 16 + fl];
    uint4 q3 = Hq[(size_t)(u3 & 0xFFFFu) * 16 + fl];
    float w0 = wdec(u0), w1 = wdec(u1), w2 = wdec(u2), w3 = wdec(u3);
    float2 t;
    t = h2f(q0.x); a0 = fmaf(w0, t.x, a0); a1 = fmaf(w0, t.y, a1);
    t = h2f(q0.y); a2 = fmaf(w0, t.x, a2); a3 = fmaf(w0, t.y, a3);
    t = h2f(q0.z); a4 = fmaf(w0, t.x, a4); a5 = fmaf(w0, t.y, a5);
    t = h2f(q0.w); a6 = fmaf(w0, t.x, a6); a7 = fmaf(w0, t.y, a7);
    t = h2f(q1.x); a0 = fmaf(w1, t.x, a0); a1 = fmaf(w1, t.y, a1);
    t = h2f(q1.y); a2 = fmaf(w1, t.x, a2); a3 = fmaf(w1, t.y, a3);
    t = h2f(q1.z); a4 = fmaf(w1, t.x, a4); a5 = fmaf(w1, t.y, a5);
    t = h2f(q1.w); a6 = fmaf(w1, t.x, a6); a7 = fmaf(w1, t.y, a7);
    t = h2f(q2.x); a0 = fmaf(w2, t.x, a0); a1 = fmaf(w2, t.y, a1);
    t = h2f(q2.y); a2 = fmaf(w2, t.x, a2); a3 = fmaf(w2, t.y, a3);
    t = h2f(q2.z); a4 = fmaf(w2, t.x, a4); a5 = fmaf(w2, t.y, a5);
    t = h2f(q2.w); a6 = fmaf(w2, t.x, a6); a7 = fmaf(w2, t.y, a7);
    t = h2f(q3.x); a0 = fmaf(w3, t.x, a0); a1 = fmaf(w3, t.y, a1);
    t = h2f(q3.y); a2 = fmaf(w3, t.x, a2); a3 = fmaf(w3, t.y, a3);
    t = h2f(q3.z); a4 = fmaf(w3, t.x, a4); a5 = fmaf(w3, t.y, a5);
    t = h2f(q3.w); a6 = fmaf(w3, t.x, a6); a7 = fmaf(w3, t.y, a7);
  }
  for (; i < e; ++i) {
    unsigned int u = csr[i];
    uint4 q = Hq[(size_t)(u & 0xFFFFu) * 16 + fl];
    float w = wdec(u);
    float2 t;
    t = h2f(q.x); a0 = fmaf(w, t.x, a0); a1 = fmaf(w, t.y, a1);
    t = h2f(q.y); a2 = fmaf(w, t.x, a2); a3 = fmaf(w, t.y, a3);
    t = h2f(q.z); a4 = fmaf(w, t.x, a4); a5 = fmaf(w, t.y, a5);
    t = h2f(q.w); a6 = fmaf(w, t.x, a6); a7 = fmaf(w, t.y, a7);
  }
  const float4* Bq = (const float4*)bias;        // 32 float4 per 128 floats
  float4 b0 = Bq[fl * 2], b1 = Bq[fl * 2 + 1];
  float4 o0 = make_float4(fmaxf(a0 + b0.x, 0.f), fmaxf(a1 + b0.y, 0.f),
                          fmaxf(a2 + b0.z, 0.f), fmaxf(a3 + b0.w, 0.f));
  float4 o1 = make_float4(fmaxf(a4 + b1.x, 0.f), fmaxf(a5 + b1.y, 0.f),
                          fmaxf(a6 + b1.z, 0.f), fmaxf(a7 + b1.w, 0.f));
  float4* Oq = (float4*)(Out + (size_t)v * 128);
  Oq[fl * 2] = o0;
  Oq[fl * 2 + 1] = o1;
}

// ---------------- aggregate 64 feats (+bias, no relu) ----------------
// 4 nodes/wave, 16 lanes/node, uint2 (4 feats) per lane.
__global__ __launch_bounds__(256) void k_agg64(const __half* __restrict__ H,
                                               const unsigned int* __restrict__ csr,
                                               const int* __restrict__ rowptr,
                                               const float* __restrict__ dis,
                                               const float* __restrict__ bias,
                                               float* __restrict__ Out, int n) {
  const int wid = threadIdx.x >> 6, lane = threadIdx.x & 63;
  const int sub = lane >> 4, fl = lane & 15;     // node-in-wave, uint2 idx
  int v = blockIdx.x * 16 + wid * 4 + sub;
  if (v >= n) return;
  int s = rowptr[v], e = rowptr[v + 1];
  float d = dis[v];
  float sw = d * d;
  const uint2* Hq = (const uint2*)H;             // 16 uint2 per 128B row
  uint2 hv = Hq[(size_t)v * 16 + fl];
  float2 p0 = h2f(hv.x), p1 = h2f(hv.y);
  float a0 = p0.x * sw, a1 = p0.y * sw, a2 = p1.x * sw, a3 = p1.y * sw;
  int i = s;
  for (; i + 4 <= e; i += 4) {
    unsigned int u0 = csr[i + 0], u1 = csr[i + 1];
    unsigned int u2 = csr[i + 2], u3 = csr[i + 3];
    uint2 q0 = Hq[(size_t)(u0 & 0xFFFFu) * 16 + fl];
    uint2 q1 = Hq[(size_t)(u1 & 0xFFFFu) * 16 + fl];
    uint2 q2 = Hq[(size_t)(u2 & 0xFFFFu) * 16 + fl];
    uint2 q3 = Hq[(size_t)(u3 & 0xFFFFu) * 16 + fl];
    float w0 = wdec(u0), w1 = wdec(u1), w2 = wdec(u2), w3 = wdec(u3);
    float2 t;
    t = h2f(q0.x); a0 = fmaf(w0, t.x, a0); a1 = fmaf(w0, t.y, a1);
    t = h2f(q0.y); a2 = fmaf(w0, t.x, a2); a3 = fmaf(w0, t.y, a3);
    t = h2f(q1.x); a0 = fmaf(w1, t.x, a0); a1 = fmaf(w1, t.y, a1);
    t = h2f(q1.y); a2 = fmaf(w1, t.x, a2); a3 = fmaf(w1, t.y, a3);
    t = h2f(q2.x); a0 = fmaf(w2, t.x, a0); a1 = fmaf(w2, t.y, a1);
    t = h2f(q2.y); a2 = fmaf(w2, t.x, a2); a3 = fmaf(w2, t.y, a3);
    t = h2f(q3.x); a0 = fmaf(w3, t.x, a0); a1 = fmaf(w3, t.y, a1);
    t = h2f(q3.y); a2 = fmaf(w3, t.x, a2); a3 = fmaf(w3, t.y, a3);
  }
  for (; i < e; ++i) {
    unsigned int u = csr[i];
    uint2 q = Hq[(size_t)(u & 0xFFFFu) * 16 + fl];
    float w = wdec(u);
    float2 t;
    t = h2f(q.x); a0 = fmaf(w, t.x, a0); a1 = fmaf(w, t.y, a1);
    t = h2f(q.y); a2 = fmaf(w, t.x, a2); a3 = fmaf(w, t.y, a3);
  }
  const float4* Bq = (const float4*)bias;        // 16 float4 per 64 floats
  float4 b = Bq[fl];
  float4 o = make_float4(a0 + b.x, a1 + b.y, a2 + b.z, a3 + b.w);
  ((float4*)(Out + (size_t)v * 64))[fl] = o;
}

extern "C" void kernel_launch(void* const* d_in, const int* in_sizes, int n_in,
                              void* d_out, int out_size, void* d_ws, size_t ws_size,
                              hipStream_t stream) {
  const float* x  = (const float*)d_in[0];
  const int*   ei = (const int*)d_in[1];    // [2, E] row-major
  const int*   row = ei;                    // edge_index[0] (source)
  const int*   col = ei + Ne;               // edge_index[1] (dest / segment)
  const float* W1 = (const float*)d_in[2];
  const float* b1 = (const float*)d_in[3];
  const float* W2 = (const float*)d_in[4];
  const float* b2 = (const float*)d_in[5];
  float* out = (float*)d_out;

  char* ws = (char*)d_ws;
  size_t off = 0;
  auto alloc = [&](size_t bytes) -> void* {
    void* p = ws + off;
    off += (bytes + 255) & ~(size_t)255;
    return p;
  };
  int*    degi   = (int*)   alloc(Nn * sizeof(int));
  int*    rowptr = (int*)   alloc((Nn + 1) * sizeof(int));
  float*  dis    = (float*) alloc(Nn * sizeof(float));
  int*    bsum   = (int*)   alloc(64 * sizeof(int));
  unsigned short* rank = (unsigned short*)alloc((size_t)Ne * sizeof(unsigned short)); // 1.6 MB
  unsigned int* csr = (unsigned int*)alloc((size_t)Ne * sizeof(unsigned int)); // 3.2 MB
  __half* H1     = (__half*)alloc((size_t)Nn * 128 * sizeof(__half));  // 12.8 MB
  float*  H1b    = (float*) alloc((size_t)Nn * 128 * sizeof(float));   // 25.6 MB
  __half* H2     = (__half*)alloc((size_t)Nn * 64 * sizeof(__half));   // 6.4 MB

  hipMemsetAsync(degi, 0, Nn * sizeof(int), stream);

  const int EB  = (Ne + 255) / 256;         // 3125
  const int NGB = (Nn + 15) / 16;           // 3125 node groups (16 nodes each)
  const int GT  = (Nn + 63) / 64;           // 782 node tiles (gemm)

  k_count<<<EB, 256, 0, stream>>>(col, degi, rank);
  k_scan1<<<SCAN_B, 1024, 0, stream>>>(degi, rowptr, dis, bsum);
  k_scan2<<<1, 64, 0, stream>>>(bsum, rowptr);
  k_scan3<<<SCAN_B, 1024, 0, stream>>>(rowptr, bsum);
  k_fill<<<EB, 256, 0, stream>>>(row, col, dis, rowptr, rank, csr);

  // layer 1: H1 = fp16(x @ W1) ; H1b = relu(agg(H1) + b1)
  k_gemm_mfma<128><<<GT, 256, 0, stream>>>(x, W1, H1, Nn);
  k_agg128<<<NGB, 256, 0, stream>>>(H1, csr, rowptr, dis, b1, H1b, Nn);

  // layer 2: H2 = fp16(H1b @ W2) ; out = agg(H2) + b2
  k_gemm_mfma<64><<<GT, 256, 0, stream>>>(H1b, W2, H2, Nn);
  k_agg64<<<NGB, 256, 0, stream>>>(H2, csr, rowptr, dis, b2, out, Nn);
}

// Round 8
// 211.301 us; speedup vs baseline: 1.3813x; 1.0480x over previous
//
#include <hip/hip_runtime.h>
#include <hip/hip_fp16.h>

// GCN, N=50000 nodes, E=800000 edges, 128->128(relu)->64, fp32 accum.
// CSR entries are 2B (src only; norm recomputed as dis[src]*dis[v] with
// dis L2-resident). k_count emits per-edge bucket rank (no atomic in fill).
// GEMMs: fp16 MFMA (v_mfma_f32_16x16x32_f16), W transposed into LDS.
// Aggregation: full-row fp16 gathers, 16B/lane, 4 nodes/wave, depth-6/8
// edge batches incl. masked tail batch (keeps memory parallelism on tails).

#define Nn 50000
#define Ne 800000
#define SCAN_B ((Nn + 1023) / 1024)   // 49 blocks

using f16x8 = _Float16 __attribute__((ext_vector_type(8)));
using f32x4 = float __attribute__((ext_vector_type(4)));

// ---------------- degree count + within-bucket rank ----------------
__global__ __launch_bounds__(256) void k_count(const int* __restrict__ col,
                                               int* __restrict__ degi,
                                               unsigned short* __restrict__ rank) {
  int e = blockIdx.x * 256 + threadIdx.x;
  if (e < Ne) rank[e] = (unsigned short)atomicAdd(&degi[col[e]], 1);
}

// ---------------- scan phase 1: block-local exclusive scan + dis ----------------
__global__ __launch_bounds__(1024) void k_scan1(const int* __restrict__ degi,
                                                int* __restrict__ rowptr,
                                                float* __restrict__ dis,
                                                int* __restrict__ bsum) {
  __shared__ int wsum[16];
  int tid = threadIdx.x;
  int lane = tid & 63, wid = tid >> 6;
  int i = blockIdx.x * 1024 + tid;
  int v = (i < Nn) ? degi[i] : 0;
  if (i < Nn) dis[i] = rsqrtf((float)(v + 1));   // self-loop adds 1
  int incl = v;
  #pragma unroll
  for (int off = 1; off < 64; off <<= 1) {
    int t = __shfl_up(incl, off);
    if (lane >= off) incl += t;
  }
  if (lane == 63) wsum[wid] = incl;
  __syncthreads();
  if (wid == 0) {
    int wv = (lane < 16) ? wsum[lane] : 0;
    #pragma unroll
    for (int off = 1; off < 16; off <<= 1) {
      int t = __shfl_up(wv, off);
      if (lane >= off) wv += t;
    }
    if (lane < 16) wsum[lane] = wv;  // inclusive over wave totals
  }
  __syncthreads();
  int woff = (wid > 0) ? wsum[wid - 1] : 0;
  if (i < Nn) rowptr[i] = woff + incl - v;       // block-local exclusive
  if (tid == 0) bsum[blockIdx.x] = wsum[15];     // block total
}

// ---------------- scan phase 2+3 fused: each block scans the 49 block sums ----------------
__global__ __launch_bounds__(1024) void k_scan3(int* __restrict__ rowptr,
                                                const int* __restrict__ bsum) {
  __shared__ int off_s;
  int tid = threadIdx.x;
  if (tid < 64) {
    int v = (tid < SCAN_B) ? bsum[tid] : 0;
    int incl = v;
    #pragma unroll
    for (int off = 1; off < 64; off <<= 1) {
      int t = __shfl_up(incl, off);
      if (tid >= off) incl += t;
    }
    if (tid == (int)blockIdx.x) off_s = incl - v;          // exclusive offset
    if (blockIdx.x == 0 && tid == SCAN_B - 1) rowptr[Nn] = incl;  // == Ne
  }
  __syncthreads();
  int i = blockIdx.x * 1024 + tid;
  if (i < Nn) rowptr[i] += off_s;
}

// ---------------- CSR fill: 2B src only, no atomic ----------------
__global__ __launch_bounds__(256) void k_fill(const int* __restrict__ row,
                                              const int* __restrict__ col,
                                              const int* __restrict__ rowptr,
                                              const unsigned short* __restrict__ rank,
                                              unsigned short* __restrict__ csr) {
  int e = blockIdx.x * 256 + threadIdx.x;
  if (e >= Ne) return;
  int r = row[e], c = col[e];
  csr[rowptr[c] + (int)rank[e]] = (unsigned short)r;
}

// ---------------- MFMA GEMM: H[n, LDO](fp16) = X[n,128] @ W[128, LDO] ----------------
// A-frag: A[m=lane&15][k=quad*8+j]; B-frag: B[k=quad*8+j][n=lane&15] (W^T in LDS)
// C/D: col=lane&15, row=quad*4+reg (m89-verified)
template <int LDO>
__global__ __launch_bounds__(256) void k_gemm_mfma(const float* __restrict__ X,
                                                   const float* __restrict__ W,
                                                   __half* __restrict__ H, int n) {
  __shared__ _Float16 Xs[64 * 136];        // 64 rows x (128+8 pad)
  __shared__ _Float16 Wts[LDO * 136];      // transposed W
  const int tid = threadIdx.x;
  const int base = blockIdx.x * 64;

  {
    constexpr int C4 = LDO / 4;
    for (int idx4 = tid; idx4 < 32 * LDO; idx4 += 256) {
      int k = idx4 / C4;
      int c = (idx4 % C4) * 4;
      float4 wv = ((const float4*)W)[idx4];
      Wts[(c + 0) * 136 + k] = (_Float16)wv.x;
      Wts[(c + 1) * 136 + k] = (_Float16)wv.y;
      Wts[(c + 2) * 136 + k] = (_Float16)wv.z;
      Wts[(c + 3) * 136 + k] = (_Float16)wv.w;
    }
  }
  {
    for (int u = tid; u < 64 * 16; u += 256) {
      int r = u >> 4, seg = u & 15;
      int node = base + r;
      if (node >= n) node = n - 1;
      const float4* xg = (const float4*)(X + (size_t)node * 128 + seg * 8);
      float4 x0 = xg[0], x1 = xg[1];
      f16x8 hv;
      hv[0] = (_Float16)x0.x; hv[1] = (_Float16)x0.y;
      hv[2] = (_Float16)x0.z; hv[3] = (_Float16)x0.w;
      hv[4] = (_Float16)x1.x; hv[5] = (_Float16)x1.y;
      hv[6] = (_Float16)x1.z; hv[7] = (_Float16)x1.w;
      *(f16x8*)&Xs[r * 136 + seg * 8] = hv;
    }
  }
  __syncthreads();

  const int w = tid >> 6, lane = tid & 63;
  const int quad = lane >> 4, mrow = lane & 15;
  constexpr int NCT = LDO / 16;

  f32x4 acc[NCT];
  #pragma unroll
  for (int ct = 0; ct < NCT; ++ct) acc[ct] = (f32x4){0.f, 0.f, 0.f, 0.f};

  #pragma unroll
  for (int ko = 0; ko < 4; ++ko) {
    f16x8 av = *(const f16x8*)&Xs[(w * 16 + mrow) * 136 + ko * 32 + quad * 8];
    #pragma unroll
    for (int ct = 0; ct < NCT; ++ct) {
      f16x8 bv = *(const f16x8*)&Wts[(ct * 16 + mrow) * 136 + ko * 32 + quad * 8];
      acc[ct] = __builtin_amdgcn_mfma_f32_16x16x32_f16(av, bv, acc[ct], 0, 0, 0);
    }
  }

  #pragma unroll
  for (int ct = 0; ct < NCT; ++ct) {
    #pragma unroll
    for (int r = 0; r < 4; ++r) {
      int node = base + w * 16 + quad * 4 + r;
      if (node < n)
        H[(size_t)node * LDO + ct * 16 + mrow] = __float2half(acc[ct][r]);
    }
  }
}

__device__ __forceinline__ float2 h2f(unsigned int u) {
  return __half22float2(*(const __half2*)&u);
}

// ---------------- aggregate 128 feats (+bias, relu) ----------------
// 4 nodes/wave, 16 lanes/node, uint4 (8 feats fp16) per lane; depth-6 edge
// batches + masked tail batch => up to 6 row-gathers + 6 dis-gathers in
// flight per node at all times.
__global__ __launch_bounds__(256) void k_agg128(const __half* __restrict__ H,
                                                const unsigned short* __restrict__ csr,
                                                const int* __restrict__ rowptr,
                                                const float* __restrict__ dis,
                                                const float* __restrict__ bias,
                                                float* __restrict__ Out, int n) {
  const int wid = threadIdx.x >> 6, lane = threadIdx.x & 63;
  const int sub = lane >> 4, fl = lane & 15;
  int v = blockIdx.x * 16 + wid * 4 + sub;
  if (v >= n) return;
  int s = rowptr[v], e = rowptr[v + 1];
  float d = dis[v];
  float sw = d * d;                              // self-loop norm = 1/deg
  const uint4* Hq = (const uint4*)H;             // 16 uint4 per 256B row
  uint4 hv = Hq[(size_t)v * 16 + fl];
  float2 p0 = h2f(hv.x), p1 = h2f(hv.y), p2 = h2f(hv.z), p3 = h2f(hv.w);
  float a0 = p0.x * sw, a1 = p0.y * sw, a2 = p1.x * sw, a3 = p1.y * sw;
  float a4 = p2.x * sw, a5 = p2.y * sw, a6 = p3.x * sw, a7 = p3.y * sw;
  constexpr int D = 6;
  int i = s;
  for (; i + D <= e; i += D) {
    int srcs[D];
    uint4 q[D];
    float wd[D];
    #pragma unroll
    for (int j = 0; j < D; ++j) srcs[j] = csr[i + j];
    #pragma unroll
    for (int j = 0; j < D; ++j) q[j] = Hq[(size_t)srcs[j] * 16 + fl];
    #pragma unroll
    for (int j = 0; j < D; ++j) wd[j] = dis[srcs[j]];
    #pragma unroll
    for (int j = 0; j < D; ++j) {
      float w = wd[j] * d;
      float2 t;
      t = h2f(q[j].x); a0 = fmaf(w, t.x, a0); a1 = fmaf(w, t.y, a1);
      t = h2f(q[j].y); a2 = fmaf(w, t.x, a2); a3 = fmaf(w, t.y, a3);
      t = h2f(q[j].z); a4 = fmaf(w, t.x, a4); a5 = fmaf(w, t.y, a5);
      t = h2f(q[j].w); a6 = fmaf(w, t.x, a6); a7 = fmaf(w, t.y, a7);
    }
  }
  if (i < e) {                                   // masked tail batch
    int srcs[D];
    uint4 q[D];
    float wd[D];
    #pragma unroll
    for (int j = 0; j < D; ++j) {
      int idx = (i + j < e) ? i + j : e - 1;
      srcs[j] = csr[idx];
    }
    #pragma unroll
    for (int j = 0; j < D; ++j) q[j] = Hq[(size_t)srcs[j] * 16 + fl];
    #pragma unroll
    for (int j = 0; j < D; ++j) wd[j] = dis[srcs[j]];
    #pragma unroll
    for (int j = 0; j < D; ++j) {
      float w = (i + j < e) ? wd[j] * d : 0.f;
      float2 t;
      t = h2f(q[j].x); a0 = fmaf(w, t.x, a0); a1 = fmaf(w, t.y, a1);
      t = h2f(q[j].y); a2 = fmaf(w, t.x, a2); a3 = fmaf(w, t.y, a3);
      t = h2f(q[j].z); a4 = fmaf(w, t.x, a4); a5 = fmaf(w, t.y, a5);
      t = h2f(q[j].w); a6 = fmaf(w, t.x, a6); a7 = fmaf(w, t.y, a7);
    }
  }
  const float4* Bq = (const float4*)bias;
  float4 b0 = Bq[fl * 2], b1 = Bq[fl * 2 + 1];
  float4 o0 = make_float4(fmaxf(a0 + b0.x, 0.f), fmaxf(a1 + b0.y, 0.f),
                          fmaxf(a2 + b0.z, 0.f), fmaxf(a3 + b0.w, 0.f));
  float4 o1 = make_float4(fmaxf(a4 + b1.x, 0.f), fmaxf(a5 + b1.y, 0.f),
                          fmaxf(a6 + b1.z, 0.f), fmaxf(a7 + b1.w, 0.f));
  float4* Oq = (float4*)(Out + (size_t)v * 128);
  Oq[fl * 2] = o0;
  Oq[fl * 2 + 1] = o1;
}

// ---------------- aggregate 64 feats (+bias, no relu) ----------------
// 4 nodes/wave, 16 lanes/node, uint2 (4 feats) per lane; depth-8 batches.
__global__ __launch_bounds__(256) void k_agg64(const __half* __restrict__ H,
                                               const unsigned short* __restrict__ csr,
                                               const int* __restrict__ rowptr,
                                               const float* __restrict__ dis,
                                               const float* __restrict__ bias,
                                               float* __restrict__ Out, int n) {
  const int wid = threadIdx.x >> 6, lane = threadIdx.x & 63;
  const int sub = lane >> 4, fl = lane & 15;
  int v = blockIdx.x * 16 + wid * 4 + sub;
  if (v >= n) return;
  int s = rowptr[v], e = rowptr[v + 1];
  float d = dis[v];
  float sw = d * d;
  const uint2* Hq = (const uint2*)H;             // 16 uint2 per 128B row
  uint2 hv = Hq[(size_t)v * 16 + fl];
  float2 p0 = h2f(hv.x), p1 = h2f(hv.y);
  float a0 = p0.x * sw, a1 = p0.y * sw, a2 = p1.x * sw, a3 = p1.y * sw;
  constexpr int D = 8;
  int i = s;
  for (; i + D <= e; i += D) {
    int srcs[D];
    uint2 q[D];
    float wd[D];
    #pragma unroll
    for (int j = 0; j < D; ++j) srcs[j] = csr[i + j];
    #pragma unroll
    for (int j = 0; j < D; ++j) q[j] = Hq[(size_t)srcs[j] * 16 + fl];
    #pragma unroll
    for (int j = 0; j < D; ++j) wd[j] = dis[srcs[j]];
    #pragma unroll
    for (int j = 0; j < D; ++j) {
      float w = wd[j] * d;
      float2 t;
      t = h2f(q[j].x); a0 = fmaf(w, t.x, a0); a1 = fmaf(w, t.y, a1);
      t = h2f(q[j].y); a2 = fmaf(w, t.x, a2); a3 = fmaf(w, t.y, a3);
    }
  }
  if (i < e) {                                   // masked tail batch
    int srcs[D];
    uint2 q[D];
    float wd[D];
    #pragma unroll
    for (int j = 0; j < D; ++j) {
      int idx = (i + j < e) ? i + j : e - 1;
      srcs[j] = csr[idx];
    }
    #pragma unroll
    for (int j = 0; j < D; ++j) q[j] = Hq[(size_t)srcs[j] * 16 + fl];
    #pragma unroll
    for (int j = 0; j < D; ++j) wd[j] = dis[srcs[j]];
    #pragma unroll
    for (int j = 0; j < D; ++j) {
      float w = (i + j < e) ? wd[j] * d : 0.f;
      float2 t;
      t = h2f(q[j].x); a0 = fmaf(w, t.x, a0); a1 = fmaf(w, t.y, a1);
      t = h2f(q[j].y); a2 = fmaf(w, t.x, a2); a3 = fmaf(w, t.y, a3);
    }
  }
  const float4* Bq = (const float4*)bias;
  float4 b = Bq[fl];
  float4 o = make_float4(a0 + b.x, a1 + b.y, a2 + b.z, a3 + b.w);
  ((float4*)(Out + (size_t)v * 64))[fl] = o;
}

extern "C" void kernel_launch(void* const* d_in, const int* in_sizes, int n_in,
                              void* d_out, int out_size, void* d_ws, size_t ws_size,
                              hipStream_t stream) {
  const float* x  = (const float*)d_in[0];
  const int*   ei = (const int*)d_in[1];    // [2, E] row-major
  const int*   row = ei;                    // edge_index[0] (source)
  const int*   col = ei + Ne;               // edge_index[1] (dest / segment)
  const float* W1 = (const float*)d_in[2];
  const float* b1 = (const float*)d_in[3];
  const float* W2 = (const float*)d_in[4];
  const float* b2 = (const float*)d_in[5];
  float* out = (float*)d_out;

  char* ws = (char*)d_ws;
  size_t off = 0;
  auto alloc = [&](size_t bytes) -> void* {
    void* p = ws + off;
    off += (bytes + 255) & ~(size_t)255;
    return p;
  };
  int*    degi   = (int*)   alloc(Nn * sizeof(int));
  int*    rowptr = (int*)   alloc((Nn + 1) * sizeof(int));
  float*  dis    = (float*) alloc(Nn * sizeof(float));
  int*    bsum   = (int*)   alloc(64 * sizeof(int));
  unsigned short* rank = (unsigned short*)alloc((size_t)Ne * sizeof(unsigned short)); // 1.6 MB
  unsigned short* csr  = (unsigned short*)alloc((size_t)Ne * sizeof(unsigned short)); // 1.6 MB
  __half* H1     = (__half*)alloc((size_t)Nn * 128 * sizeof(__half));  // 12.8 MB
  float*  H1b    = (float*) alloc((size_t)Nn * 128 * sizeof(float));   // 25.6 MB
  __half* H2     = (__half*)alloc((size_t)Nn * 64 * sizeof(__half));   // 6.4 MB

  hipMemsetAsync(degi, 0, Nn * sizeof(int), stream);

  const int EB  = (Ne + 255) / 256;         // 3125
  const int NGB = (Nn + 15) / 16;           // 3125 node groups (16 nodes each)
  const int GT  = (Nn + 63) / 64;           // 782 node tiles (gemm)

  k_count<<<EB, 256, 0, stream>>>(col, degi, rank);
  k_scan1<<<SCAN_B, 1024, 0, stream>>>(degi, rowptr, dis, bsum);
  k_scan3<<<SCAN_B, 1024, 0, stream>>>(rowptr, bsum);
  k_fill<<<EB, 256, 0, stream>>>(row, col, rowptr, rank, csr);

  // layer 1: H1 = fp16(x @ W1) ; H1b = relu(agg(H1) + b1)
  k_gemm_mfma<128><<<GT, 256, 0, stream>>>(x, W1, H1, Nn);
  k_agg128<<<NGB, 256, 0, stream>>>(H1, csr, rowptr, dis, b1, H1b, Nn);

  // layer 2: H2 = fp16(H1b @ W2) ; out = agg(H2) + b2
  k_gemm_mfma<64><<<GT, 256, 0, stream>>>(H1b, W2, H2, Nn);
  k_agg64<<<NGB, 256, 0, stream>>>(H2, csr, rowptr, dis, b2, out, Nn);
}

// Round 9
// 207.502 us; speedup vs baseline: 1.4066x; 1.0183x over previous
//
#include <hip/hip_runtime.h>
#include <hip/hip_fp16.h>

// GCN, N=50000 nodes, E=800000 edges, 128->128(relu)->64, fp32 accum.
// CSR entries are 2B (src only; norm recomputed as dis[src]*dis[v]).
// k_count emits per-edge bucket rank (no atomic in fill).
// Layer 1: fp16 MFMA GEMM (x@W1 -> H1 fp16).
// Fused kernel: agg(H1)+b1+relu per 16-node block tile -> LDS fp16 ->
//   MFMA x W2^T (LDS) -> H2 fp16 directly (H1b buffer eliminated).
// Layer 2 agg: gather H2, +b2 -> out.

#define Nn 50000
#define Ne 800000
#define SCAN_B ((Nn + 1023) / 1024)   // 49 blocks

using f16x8 = _Float16 __attribute__((ext_vector_type(8)));
using f32x4 = float __attribute__((ext_vector_type(4)));

// ---------------- degree count + within-bucket rank ----------------
__global__ __launch_bounds__(256) void k_count(const int* __restrict__ col,
                                               int* __restrict__ degi,
                                               unsigned short* __restrict__ rank) {
  int e = blockIdx.x * 256 + threadIdx.x;
  if (e < Ne) rank[e] = (unsigned short)atomicAdd(&degi[col[e]], 1);
}

// ---------------- scan phase 1: block-local exclusive scan + dis ----------------
__global__ __launch_bounds__(1024) void k_scan1(const int* __restrict__ degi,
                                                int* __restrict__ rowptr,
                                                float* __restrict__ dis,
                                                int* __restrict__ bsum) {
  __shared__ int wsum[16];
  int tid = threadIdx.x;
  int lane = tid & 63, wid = tid >> 6;
  int i = blockIdx.x * 1024 + tid;
  int v = (i < Nn) ? degi[i] : 0;
  if (i < Nn) dis[i] = rsqrtf((float)(v + 1));   // self-loop adds 1
  int incl = v;
  #pragma unroll
  for (int off = 1; off < 64; off <<= 1) {
    int t = __shfl_up(incl, off);
    if (lane >= off) incl += t;
  }
  if (lane == 63) wsum[wid] = incl;
  __syncthreads();
  if (wid == 0) {
    int wv = (lane < 16) ? wsum[lane] : 0;
    #pragma unroll
    for (int off = 1; off < 16; off <<= 1) {
      int t = __shfl_up(wv, off);
      if (lane >= off) wv += t;
    }
    if (lane < 16) wsum[lane] = wv;  // inclusive over wave totals
  }
  __syncthreads();
  int woff = (wid > 0) ? wsum[wid - 1] : 0;
  if (i < Nn) rowptr[i] = woff + incl - v;       // block-local exclusive
  if (tid == 0) bsum[blockIdx.x] = wsum[15];     // block total
}

// ---------------- scan phase 2+3 fused: each block scans the 49 block sums ----------------
__global__ __launch_bounds__(1024) void k_scan3(int* __restrict__ rowptr,
                                                const int* __restrict__ bsum) {
  __shared__ int off_s;
  int tid = threadIdx.x;
  if (tid < 64) {
    int v = (tid < SCAN_B) ? bsum[tid] : 0;
    int incl = v;
    #pragma unroll
    for (int off = 1; off < 64; off <<= 1) {
      int t = __shfl_up(incl, off);
      if (tid >= off) incl += t;
    }
    if (tid == (int)blockIdx.x) off_s = incl - v;          // exclusive offset
    if (blockIdx.x == 0 && tid == SCAN_B - 1) rowptr[Nn] = incl;  // == Ne
  }
  __syncthreads();
  int i = blockIdx.x * 1024 + tid;
  if (i < Nn) rowptr[i] += off_s;
}

// ---------------- CSR fill: 2B src only, no atomic ----------------
__global__ __launch_bounds__(256) void k_fill(const int* __restrict__ row,
                                              const int* __restrict__ col,
                                              const int* __restrict__ rowptr,
                                              const unsigned short* __restrict__ rank,
                                              unsigned short* __restrict__ csr) {
  int e = blockIdx.x * 256 + threadIdx.x;
  if (e >= Ne) return;
  int r = row[e], c = col[e];
  csr[rowptr[c] + (int)rank[e]] = (unsigned short)r;
}

// ---------------- MFMA GEMM: H[n, LDO](fp16) = X[n,128] @ W[128, LDO] ----------------
// A-frag: A[m=lane&15][k=quad*8+j]; B-frag: B[k=quad*8+j][n=lane&15] (W^T in LDS)
// C/D: col=lane&15, row=quad*4+reg (m89-verified)
template <int LDO>
__global__ __launch_bounds__(256) void k_gemm_mfma(const float* __restrict__ X,
                                                   const float* __restrict__ W,
                                                   __half* __restrict__ H, int n) {
  __shared__ _Float16 Xs[64 * 136];        // 64 rows x (128+8 pad)
  __shared__ _Float16 Wts[LDO * 136];      // transposed W
  const int tid = threadIdx.x;
  const int base = blockIdx.x * 64;

  {
    constexpr int C4 = LDO / 4;
    for (int idx4 = tid; idx4 < 32 * LDO; idx4 += 256) {
      int k = idx4 / C4;
      int c = (idx4 % C4) * 4;
      float4 wv = ((const float4*)W)[idx4];
      Wts[(c + 0) * 136 + k] = (_Float16)wv.x;
      Wts[(c + 1) * 136 + k] = (_Float16)wv.y;
      Wts[(c + 2) * 136 + k] = (_Float16)wv.z;
      Wts[(c + 3) * 136 + k] = (_Float16)wv.w;
    }
  }
  {
    for (int u = tid; u < 64 * 16; u += 256) {
      int r = u >> 4, seg = u & 15;
      int node = base + r;
      if (node >= n) node = n - 1;
      const float4* xg = (const float4*)(X + (size_t)node * 128 + seg * 8);
      float4 x0 = xg[0], x1 = xg[1];
      f16x8 hv;
      hv[0] = (_Float16)x0.x; hv[1] = (_Float16)x0.y;
      hv[2] = (_Float16)x0.z; hv[3] = (_Float16)x0.w;
      hv[4] = (_Float16)x1.x; hv[5] = (_Float16)x1.y;
      hv[6] = (_Float16)x1.z; hv[7] = (_Float16)x1.w;
      *(f16x8*)&Xs[r * 136 + seg * 8] = hv;
    }
  }
  __syncthreads();

  const int w = tid >> 6, lane = tid & 63;
  const int quad = lane >> 4, mrow = lane & 15;
  constexpr int NCT = LDO / 16;

  f32x4 acc[NCT];
  #pragma unroll
  for (int ct = 0; ct < NCT; ++ct) acc[ct] = (f32x4){0.f, 0.f, 0.f, 0.f};

  #pragma unroll
  for (int ko = 0; ko < 4; ++ko) {
    f16x8 av = *(const f16x8*)&Xs[(w * 16 + mrow) * 136 + ko * 32 + quad * 8];
    #pragma unroll
    for (int ct = 0; ct < NCT; ++ct) {
      f16x8 bv = *(const f16x8*)&Wts[(ct * 16 + mrow) * 136 + ko * 32 + quad * 8];
      acc[ct] = __builtin_amdgcn_mfma_f32_16x16x32_f16(av, bv, acc[ct], 0, 0, 0);
    }
  }

  #pragma unroll
  for (int ct = 0; ct < NCT; ++ct) {
    #pragma unroll
    for (int r = 0; r < 4; ++r) {
      int node = base + w * 16 + quad * 4 + r;
      if (node < n)
        H[(size_t)node * LDO + ct * 16 + mrow] = __float2half(acc[ct][r]);
    }
  }
}

__device__ __forceinline__ float2 h2f(unsigned int u) {
  return __half22float2(*(const __half2*)&u);
}

// ---------------- FUSED: agg128(+b1, relu) -> LDS fp16 -> MFMA @ W2 -> H2 fp16 ----------------
// Stage A (agg): 4 nodes/wave, 16 lanes/node, uint4 (8 fp16 feats)/lane,
//   depth-6 edge batches + masked tail => 12 gathers in flight per node.
// Stage B (gemm): block's 16-node x 128 tile -> LDS; wave w computes output
//   col-tile [w*16, w*16+16) via 4x mfma_f32_16x16x32_f16 against W2^T (LDS).
// Nn = 50000 = 3125 * 16 exactly -> no partial blocks.
__global__ __launch_bounds__(256) void k_agg128_gemm64(
    const __half* __restrict__ H, const unsigned short* __restrict__ csr,
    const int* __restrict__ rowptr, const float* __restrict__ dis,
    const float* __restrict__ bias, const float* __restrict__ W2,
    __half* __restrict__ H2, int n) {
  __shared__ _Float16 Wts[64 * 136];   // W2 transposed: [c][k]
  __shared__ _Float16 Hs[16 * 136];    // block's 16 aggregated rows (fp16)

  const int tid = threadIdx.x;
  const int wid = tid >> 6, lane = tid & 63;
  const int sub = lane >> 4, fl = lane & 15;
  const int nb = wid * 4 + sub;                  // node-in-block [0,16)
  const int v = blockIdx.x * 16 + nb;

  // stage W2^T (fp32 [128][64] -> fp16 Wts[c][k]); 2048 float4, 8/thread
  for (int idx4 = tid; idx4 < 2048; idx4 += 256) {
    int k = idx4 >> 4;
    int c = (idx4 & 15) * 4;
    float4 wv = ((const float4*)W2)[idx4];
    Wts[(c + 0) * 136 + k] = (_Float16)wv.x;
    Wts[(c + 1) * 136 + k] = (_Float16)wv.y;
    Wts[(c + 2) * 136 + k] = (_Float16)wv.z;
    Wts[(c + 3) * 136 + k] = (_Float16)wv.w;
  }

  // ---- stage A: aggregate node v's 8 feats per lane ----
  float a0 = 0, a1 = 0, a2 = 0, a3 = 0, a4 = 0, a5 = 0, a6 = 0, a7 = 0;
  float d = 0.f;
  if (v < n) {
    int s = rowptr[v], e = rowptr[v + 1];
    d = dis[v];
    float sw = d * d;                            // self-loop norm = 1/deg
    const uint4* Hq = (const uint4*)H;           // 16 uint4 per 256B row
    uint4 hv = Hq[(size_t)v * 16 + fl];
    float2 p0 = h2f(hv.x), p1 = h2f(hv.y), p2 = h2f(hv.z), p3 = h2f(hv.w);
    a0 = p0.x * sw; a1 = p0.y * sw; a2 = p1.x * sw; a3 = p1.y * sw;
    a4 = p2.x * sw; a5 = p2.y * sw; a6 = p3.x * sw; a7 = p3.y * sw;
    constexpr int D = 6;
    int i = s;
    for (; i + D <= e; i += D) {
      int srcs[D];
      uint4 q[D];
      float wd[D];
      #pragma unroll
      for (int j = 0; j < D; ++j) srcs[j] = csr[i + j];
      #pragma unroll
      for (int j = 0; j < D; ++j) q[j] = Hq[(size_t)srcs[j] * 16 + fl];
      #pragma unroll
      for (int j = 0; j < D; ++j) wd[j] = dis[srcs[j]];
      #pragma unroll
      for (int j = 0; j < D; ++j) {
        float w = wd[j] * d;
        float2 t;
        t = h2f(q[j].x); a0 = fmaf(w, t.x, a0); a1 = fmaf(w, t.y, a1);
        t = h2f(q[j].y); a2 = fmaf(w, t.x, a2); a3 = fmaf(w, t.y, a3);
        t = h2f(q[j].z); a4 = fmaf(w, t.x, a4); a5 = fmaf(w, t.y, a5);
        t = h2f(q[j].w); a6 = fmaf(w, t.x, a6); a7 = fmaf(w, t.y, a7);
      }
    }
    if (i < e) {                                 // masked tail batch
      int srcs[D];
      uint4 q[D];
      float wd[D];
      #pragma unroll
      for (int j = 0; j < D; ++j) {
        int idx = (i + j < e) ? i + j : e - 1;
        srcs[j] = csr[idx];
      }
      #pragma unroll
      for (int j = 0; j < D; ++j) q[j] = Hq[(size_t)srcs[j] * 16 + fl];
      #pragma unroll
      for (int j = 0; j < D; ++j) wd[j] = dis[srcs[j]];
      #pragma unroll
      for (int j = 0; j < D; ++j) {
        float w = (i + j < e) ? wd[j] * d : 0.f;
        float2 t;
        t = h2f(q[j].x); a0 = fmaf(w, t.x, a0); a1 = fmaf(w, t.y, a1);
        t = h2f(q[j].y); a2 = fmaf(w, t.x, a2); a3 = fmaf(w, t.y, a3);
        t = h2f(q[j].z); a4 = fmaf(w, t.x, a4); a5 = fmaf(w, t.y, a5);
        t = h2f(q[j].w); a6 = fmaf(w, t.x, a6); a7 = fmaf(w, t.y, a7);
      }
    }
  }
  // +b1, relu, fp16 -> LDS row nb
  {
    const float4* Bq = (const float4*)bias;
    float4 b0 = Bq[fl * 2], b1v = Bq[fl * 2 + 1];
    f16x8 hrow;
    hrow[0] = (_Float16)fmaxf(a0 + b0.x, 0.f);
    hrow[1] = (_Float16)fmaxf(a1 + b0.y, 0.f);
    hrow[2] = (_Float16)fmaxf(a2 + b0.z, 0.f);
    hrow[3] = (_Float16)fmaxf(a3 + b0.w, 0.f);
    hrow[4] = (_Float16)fmaxf(a4 + b1v.x, 0.f);
    hrow[5] = (_Float16)fmaxf(a5 + b1v.y, 0.f);
    hrow[6] = (_Float16)fmaxf(a6 + b1v.z, 0.f);
    hrow[7] = (_Float16)fmaxf(a7 + b1v.w, 0.f);
    *(f16x8*)&Hs[nb * 136 + fl * 8] = hrow;
  }
  __syncthreads();

  // ---- stage B: 16x64 = (16x128) @ (128x64), wave w -> cols [w*16, w*16+16) ----
  const int quad = lane >> 4, mrow = lane & 15;
  f32x4 acc = (f32x4){0.f, 0.f, 0.f, 0.f};
  #pragma unroll
  for (int ko = 0; ko < 4; ++ko) {
    f16x8 av = *(const f16x8*)&Hs[mrow * 136 + ko * 32 + quad * 8];
    f16x8 bv = *(const f16x8*)&Wts[(wid * 16 + mrow) * 136 + ko * 32 + quad * 8];
    acc = __builtin_amdgcn_mfma_f32_16x16x32_f16(av, bv, acc, 0, 0, 0);
  }
  #pragma unroll
  for (int r = 0; r < 4; ++r) {
    int node = blockIdx.x * 16 + quad * 4 + r;
    if (node < n)
      H2[(size_t)node * 64 + wid * 16 + mrow] = __float2half(acc[r]);
  }
}

// ---------------- aggregate 64 feats (+bias, no relu) ----------------
// 4 nodes/wave, 16 lanes/node, uint2 (4 feats) per lane; depth-8 batches.
__global__ __launch_bounds__(256) void k_agg64(const __half* __restrict__ H,
                                               const unsigned short* __restrict__ csr,
                                               const int* __restrict__ rowptr,
                                               const float* __restrict__ dis,
                                               const float* __restrict__ bias,
                                               float* __restrict__ Out, int n) {
  const int wid = threadIdx.x >> 6, lane = threadIdx.x & 63;
  const int sub = lane >> 4, fl = lane & 15;
  int v = blockIdx.x * 16 + wid * 4 + sub;
  if (v >= n) return;
  int s = rowptr[v], e = rowptr[v + 1];
  float d = dis[v];
  float sw = d * d;
  const uint2* Hq = (const uint2*)H;             // 16 uint2 per 128B row
  uint2 hv = Hq[(size_t)v * 16 + fl];
  float2 p0 = h2f(hv.x), p1 = h2f(hv.y);
  float a0 = p0.x * sw, a1 = p0.y * sw, a2 = p1.x * sw, a3 = p1.y * sw;
  constexpr int D = 8;
  int i = s;
  for (; i + D <= e; i += D) {
    int srcs[D];
    uint2 q[D];
    float wd[D];
    #pragma unroll
    for (int j = 0; j < D; ++j) srcs[j] = csr[i + j];
    #pragma unroll
    for (int j = 0; j < D; ++j) q[j] = Hq[(size_t)srcs[j] * 16 + fl];
    #pragma unroll
    for (int j = 0; j < D; ++j) wd[j] = dis[srcs[j]];
    #pragma unroll
    for (int j = 0; j < D; ++j) {
      float w = wd[j] * d;
      float2 t;
      t = h2f(q[j].x); a0 = fmaf(w, t.x, a0); a1 = fmaf(w, t.y, a1);
      t = h2f(q[j].y); a2 = fmaf(w, t.x, a2); a3 = fmaf(w, t.y, a3);
    }
  }
  if (i < e) {                                   // masked tail batch
    int srcs[D];
    uint2 q[D];
    float wd[D];
    #pragma unroll
    for (int j = 0; j < D; ++j) {
      int idx = (i + j < e) ? i + j : e - 1;
      srcs[j] = csr[idx];
    }
    #pragma unroll
    for (int j = 0; j < D; ++j) q[j] = Hq[(size_t)srcs[j] * 16 + fl];
    #pragma unroll
    for (int j = 0; j < D; ++j) wd[j] = dis[srcs[j]];
    #pragma unroll
    for (int j = 0; j < D; ++j) {
      float w = (i + j < e) ? wd[j] * d : 0.f;
      float2 t;
      t = h2f(q[j].x); a0 = fmaf(w, t.x, a0); a1 = fmaf(w, t.y, a1);
      t = h2f(q[j].y); a2 = fmaf(w, t.x, a2); a3 = fmaf(w, t.y, a3);
    }
  }
  const float4* Bq = (const float4*)bias;
  float4 b = Bq[fl];
  float4 o = make_float4(a0 + b.x, a1 + b.y, a2 + b.z, a3 + b.w);
  ((float4*)(Out + (size_t)v * 64))[fl] = o;
}

extern "C" void kernel_launch(void* const* d_in, const int* in_sizes, int n_in,
                              void* d_out, int out_size, void* d_ws, size_t ws_size,
                              hipStream_t stream) {
  const float* x  = (const float*)d_in[0];
  const int*   ei = (const int*)d_in[1];    // [2, E] row-major
  const int*   row = ei;                    // edge_index[0] (source)
  const int*   col = ei + Ne;               // edge_index[1] (dest / segment)
  const float* W1 = (const float*)d_in[2];
  const float* b1 = (const float*)d_in[3];
  const float* W2 = (const float*)d_in[4];
  const float* b2 = (const float*)d_in[5];
  float* out = (float*)d_out;

  char* ws = (char*)d_ws;
  size_t off = 0;
  auto alloc = [&](size_t bytes) -> void* {
    void* p = ws + off;
    off += (bytes + 255) & ~(size_t)255;
    return p;
  };
  int*    degi   = (int*)   alloc(Nn * sizeof(int));
  int*    rowptr = (int*)   alloc((Nn + 1) * sizeof(int));
  float*  dis    = (float*) alloc(Nn * sizeof(float));
  int*    bsum   = (int*)   alloc(64 * sizeof(int));
  unsigned short* rank = (unsigned short*)alloc((size_t)Ne * sizeof(unsigned short)); // 1.6 MB
  unsigned short* csr  = (unsigned short*)alloc((size_t)Ne * sizeof(unsigned short)); // 1.6 MB
  __half* H1     = (__half*)alloc((size_t)Nn * 128 * sizeof(__half));  // 12.8 MB
  __half* H2     = (__half*)alloc((size_t)Nn * 64 * sizeof(__half));   // 6.4 MB

  hipMemsetAsync(degi, 0, Nn * sizeof(int), stream);

  const int EB  = (Ne + 255) / 256;         // 3125
  const int NGB = (Nn + 15) / 16;           // 3125 node groups (16 nodes each)
  const int GT  = (Nn + 63) / 64;           // 782 node tiles (gemm)

  k_count<<<EB, 256, 0, stream>>>(col, degi, rank);
  k_scan1<<<SCAN_B, 1024, 0, stream>>>(degi, rowptr, dis, bsum);
  k_scan3<<<SCAN_B, 1024, 0, stream>>>(rowptr, bsum);
  k_fill<<<EB, 256, 0, stream>>>(row, col, rowptr, rank, csr);

  // layer 1 GEMM: H1 = fp16(x @ W1)
  k_gemm_mfma<128><<<GT, 256, 0, stream>>>(x, W1, H1, Nn);
  // fused: H2 = fp16( relu(agg(H1) + b1) @ W2 )
  k_agg128_gemm64<<<NGB, 256, 0, stream>>>(H1, csr, rowptr, dis, b1, W2, H2, Nn);
  // layer 2 agg: out = agg(H2) + b2
  k_agg64<<<NGB, 256, 0, stream>>>(H2, csr, rowptr, dis, b2, out, Nn);
}